// Round 6
// baseline (478.312 us; speedup 1.0000x reference)
//
#include <hip/hip_runtime.h>
#include <math.h>

namespace {

constexpr int NROWS = 2048;   // B*T
constexpr int DIN   = 512;
constexpr int DOUT  = 512;
constexpr int HEADS = 4;
constexpr int KDIM  = 512;
constexpr int HALFD = 256;
constexpr int NKEYS = 512;
constexpr int KNN   = 32;
constexpr int MARG  = 40;     // candidate margin for approx stage-1

typedef short bf16x8 __attribute__((ext_vector_type(8)));
typedef float f32x4  __attribute__((ext_vector_type(4)));

__device__ inline unsigned short f2bf(float f) {   // round-to-nearest-even
    unsigned u = __float_as_uint(f);
    unsigned r = u + 0x7FFFu + ((u >> 16) & 1u);
    return (unsigned short)(r >> 16);
}
__device__ inline unsigned fmap(float f) {
    unsigned u = __float_as_uint(f);
    return (u & 0x80000000u) ? ~u : (u | 0x80000000u);
}
__device__ inline float funmap(unsigned m) {
    unsigned u = (m & 0x80000000u) ? (m & 0x7FFFFFFFu) : ~m;
    return __uint_as_float(u);
}
__device__ inline unsigned long long shflxor64(unsigned long long x, int m) {
    unsigned lo = (unsigned)x, hi = (unsigned)(x >> 32);
    lo = __shfl_xor(lo, m);
    hi = __shfl_xor(hi, m);
    return ((unsigned long long)hi << 32) | lo;
}

// =================== keys f32 -> bf16 ======================================
__global__ __launch_bounds__(256)
void convert_keys(const float* __restrict__ k, unsigned short* __restrict__ kb)
{
    const int i = (blockIdx.x * 256 + threadIdx.x) * 4;   // 1024 blocks cover 1M
    const float4 v = *(const float4*)(k + i);
    ushort4 o;
    o.x = f2bf(v.x); o.y = f2bf(v.y); o.z = f2bf(v.z); o.w = f2bf(v.w);
    *(ushort4*)(kb + i) = o;
}

// =================== big-tile f32 NT GEMM body: 128x64, 8x4 micro ==========
// R4-proven single-buffer + reg prefetch.  EPI 0: +bias.  EPI 1: silu.
// EPI 2: +bias, dual-store f32 C and bf16 Cb.
template<int EPI>
__device__ inline void gemm128x64_body(const float* __restrict__ A, int lda,
                                       const float* __restrict__ B, int ldb,
                                       float* __restrict__ C, int ldc,
                                       unsigned short* __restrict__ Cb,
                                       const float* __restrict__ bias, int K,
                                       int m0, int n0)
{
    __shared__ __align__(16) float as[16][132];
    __shared__ __align__(16) float bs[16][68];
    const int tid = threadIdx.x;
    const int tx = tid & 15;          // n: 4 cols each
    const int ty = tid >> 4;          // m: 8 rows each
    const int lrA = tid >> 1, lkA = (tid & 1) << 3;
    const int lrB = tid >> 2, lkB = (tid & 3) << 2;
    const float* Ap = A + (size_t)(m0 + lrA) * lda + lkA;
    const float* Bp = B + (size_t)(n0 + lrB) * ldb + lkB;
    float acc[8][4] = {};

    float4 a0 = *(const float4*)(Ap);
    float4 a1 = *(const float4*)(Ap + 4);
    float4 b0 = *(const float4*)(Bp);

    for (int k0 = 0; k0 < K; k0 += 16) {
        __syncthreads();
        as[lkA + 0][lrA] = a0.x; as[lkA + 1][lrA] = a0.y;
        as[lkA + 2][lrA] = a0.z; as[lkA + 3][lrA] = a0.w;
        as[lkA + 4][lrA] = a1.x; as[lkA + 5][lrA] = a1.y;
        as[lkA + 6][lrA] = a1.z; as[lkA + 7][lrA] = a1.w;
        bs[lkB + 0][lrB] = b0.x; bs[lkB + 1][lrB] = b0.y;
        bs[lkB + 2][lrB] = b0.z; bs[lkB + 3][lrB] = b0.w;
        __syncthreads();
        if (k0 + 16 < K) {
            a0 = *(const float4*)(Ap + k0 + 16);
            a1 = *(const float4*)(Ap + k0 + 20);
            b0 = *(const float4*)(Bp + k0 + 16);
        }
        #pragma unroll
        for (int kk = 0; kk < 16; ++kk) {
            const float4 a0v = *(const float4*)&as[kk][ty << 3];
            const float4 a1v = *(const float4*)&as[kk][(ty << 3) + 4];
            const float4 bv  = *(const float4*)&bs[kk][tx << 2];
            const float ar[8] = {a0v.x, a0v.y, a0v.z, a0v.w,
                                 a1v.x, a1v.y, a1v.z, a1v.w};
            const float br[4] = {bv.x, bv.y, bv.z, bv.w};
            #pragma unroll
            for (int i = 0; i < 8; ++i)
                #pragma unroll
                for (int j = 0; j < 4; ++j)
                    acc[i][j] = fmaf(ar[i], br[j], acc[i][j]);
        }
    }

    float4 bb = {0.f, 0.f, 0.f, 0.f};
    if (bias) bb = *(const float4*)(bias + n0 + (tx << 2));
    #pragma unroll
    for (int i = 0; i < 8; ++i) {
        float4 o;
        o.x = acc[i][0] + bb.x; o.y = acc[i][1] + bb.y;
        o.z = acc[i][2] + bb.z; o.w = acc[i][3] + bb.w;
        if (EPI == 1) {
            o.x = o.x / (1.f + expf(-o.x));
            o.y = o.y / (1.f + expf(-o.y));
            o.z = o.z / (1.f + expf(-o.z));
            o.w = o.w / (1.f + expf(-o.w));
        }
        const size_t off = (size_t)(m0 + (ty << 3) + i) * ldc + n0 + (tx << 2);
        *(float4*)(C + off) = o;
        if (EPI == 2) {
            ushort4 ob;
            ob.x = f2bf(o.x); ob.y = f2bf(o.y);
            ob.z = f2bf(o.z); ob.w = f2bf(o.w);
            *(ushort4*)(Cb + off) = ob;
        }
    }
}

// z==0: q = x@Wq^T + bq (dual f32+bf16)   z==1: gate = silu(x@Wsw^T + bsw)
__global__ __launch_bounds__(256)
void qgate_gemm(const float* __restrict__ x,
                const float* __restrict__ Wq, const float* __restrict__ bq,
                const float* __restrict__ Wsw, const float* __restrict__ bsw,
                float* __restrict__ q, unsigned short* __restrict__ qb,
                float* __restrict__ gate)
{
    if (blockIdx.z == 0) {
        gemm128x64_body<2>(x, DIN, Wq, DIN, q, HEADS * KDIM, qb, bq, DIN,
                           blockIdx.y * 128, blockIdx.x * 64);
    } else {
        if (blockIdx.x >= 8) return;
        gemm128x64_body<1>(x, DIN, Wsw, DIN, gate, DOUT, nullptr, bsw, DIN,
                           blockIdx.y * 128, blockIdx.x * 64);
    }
}

// =================== approx score GEMM via bf16 MFMA =======================
// s_z = q_z(bf16) @ keys_z(bf16)^T, f32 out.  Wave: 16(M)x64(N), K=256.
// A-frag: lane row=l&15, k=(l>>4)*8+j.  B-frag: lane col=l&15, same k.
// C: col=l&15, row=(l>>4)*4+r  [m89/m91-verified].
__global__ __launch_bounds__(256)
void score_mfma(const unsigned short* __restrict__ qb,
                const unsigned short* __restrict__ kb,
                float* __restrict__ s)
{
    const int wave = threadIdx.x >> 6;
    const int lane = threadIdx.x & 63;
    const int z  = blockIdx.z;
    const int m0 = blockIdx.x * 64 + wave * 16;
    const int n0 = blockIdx.y * 64;
    const int r16 = lane & 15;
    const int kc  = lane >> 4;

    const unsigned short* ap = qb + (size_t)(m0 + r16) * (HEADS * KDIM)
                             + (z >> 1) * KDIM + (z & 1) * HALFD + kc * 8;
    const unsigned short* bp = kb + ((size_t)z * NKEYS + n0 + r16) * HALFD + kc * 8;

    f32x4 acc[4] = {{0,0,0,0},{0,0,0,0},{0,0,0,0},{0,0,0,0}};
    #pragma unroll
    for (int kk = 0; kk < 8; ++kk) {
        const bf16x8 a = *(const bf16x8*)(ap + kk * 32);
        #pragma unroll
        for (int t = 0; t < 4; ++t) {
            const bf16x8 b = *(const bf16x8*)(bp + (size_t)t * 16 * HALFD + kk * 32);
            acc[t] = __builtin_amdgcn_mfma_f32_16x16x32_bf16(a, b, acc[t], 0, 0, 0);
        }
    }
    #pragma unroll
    for (int t = 0; t < 4; ++t)
        #pragma unroll
        for (int r = 0; r < 4; ++r)
            s[(size_t)(m0 + kc * 4 + r) * (HEADS * 2 * NKEYS)
              + z * NKEYS + n0 + t * 16 + r16] = acc[t][r];
}

// =================== top-k: approx top-40 -> exact rescore -> exact top-32 =
// One 64-lane wave per (n,h); 32-lane subgroup per half.
__global__ __launch_bounds__(64)
void topk_kernel(const float* __restrict__ s, const float* __restrict__ q,
                 const float* __restrict__ keys,
                 float* __restrict__ w_out, int* __restrict__ idx_out)
{
    const int nh   = blockIdx.x;
    const int n    = nh >> 2;
    const int h    = nh & 3;
    const int lane = threadIdx.x;
    const int sub  = lane >> 5;
    const int sl   = lane & 31;
    __shared__ float qlds[KDIM];
    __shared__ int   ci[2][MARG];
    __shared__ float exv[2][MARG];
    __shared__ float ts[2][KNN];
    __shared__ int   ti[2][KNN];

    // stage q row (f32) for rescore
    const float* qrow = q + (size_t)n * (HEADS * KDIM) + h * KDIM;
    #pragma unroll
    for (int j = 0; j < 8; ++j) qlds[j * 64 + lane] = qrow[j * 64 + lane];

    // ---- stage A: approx top-40 per half (indices only) ----
    const float* sb = s + (size_t)nh * (2 * NKEYS) + sub * NKEYS;
    float v[16];
    #pragma unroll
    for (int i = 0; i < 16; ++i) v[i] = sb[i * 32 + sl];
    unsigned used = 0;
    for (int it = 0; it < MARG; ++it) {
        float bv = -INFINITY; int bi = 0;
        #pragma unroll
        for (int i = 0; i < 16; ++i) {
            const bool ok = !((used >> i) & 1u) && v[i] > bv;
            bv = ok ? v[i] : bv;
            bi = ok ? i : bi;
        }
        float m = bv;
        #pragma unroll
        for (int off = 16; off; off >>= 1) m = fmaxf(m, __shfl_xor(m, off));
        const int cand = (bv == m) ? ((bi << 5) | sl) : 0x7fffffff;
        const unsigned long long bal = __ballot(bv == m);
        const unsigned half = (unsigned)(bal >> (sub << 5));
        int e;
        if (__popc(half) == 1) {
            e = __shfl(cand, (sub << 5) + (__ffs(half) - 1));
        } else {
            int cm = cand;
            #pragma unroll
            for (int off = 16; off; off >>= 1) cm = min(cm, __shfl_xor(cm, off));
            e = cm;
        }
        if (sl == 0) ci[sub][it] = e;
        if (sl == (e & 31)) used |= 1u << (e >> 5);
    }
    __syncthreads();

    // ---- stage B: exact f32 rescore (ascending-k fmaf chain == R2 GEMM) ----
    #pragma unroll
    for (int pass = 0; pass < 2; ++pass) {
        const int c = pass * 64 + lane;
        if (c < 2 * MARG) {
            const int chalf = c / MARG, slot = c - chalf * MARG;
            const int cidx = ci[chalf][slot];
            const float* kr = keys
                + ((size_t)(h * 2 + chalf) * NKEYS + cidx) * HALFD;
            const float* qh = qlds + chalf * HALFD;
            float a = 0.f;
            #pragma unroll 4
            for (int k = 0; k < HALFD; ++k) a = fmaf(qh[k], kr[k], a);
            exv[chalf][slot] = a;
        }
    }
    __syncthreads();

    // ---- stage C: exact top-32 of the 40 (value desc, index asc) ----
    unsigned long long pk0 = 0ull, pk1 = 0ull;
    if (sl < MARG)
        pk0 = ((unsigned long long)fmap(exv[sub][sl]) << 32)
            | (unsigned)(~ci[sub][sl]);
    if (sl + 32 < MARG)
        pk1 = ((unsigned long long)fmap(exv[sub][sl + 32]) << 32)
            | (unsigned)(~ci[sub][sl + 32]);
    for (int it = 0; it < KNN; ++it) {
        unsigned long long best = pk0 > pk1 ? pk0 : pk1;
        #pragma unroll
        for (int off = 16; off; off >>= 1) {
            const unsigned long long o = shflxor64(best, off);
            if (o > best) best = o;
        }
        if (sl == 0) {
            ts[sub][it] = funmap((unsigned)(best >> 32));
            ti[sub][it] = (int)(~(unsigned)best) & (NKEYS - 1);
        }
        if (pk0 == best) pk0 = 0ull;
        if (pk1 == best) pk1 = 0ull;
    }
    __syncthreads();

    // ---- stage 2: top-32 of the 119 pruned cartesian sums (R2-verified) ----
    float cv[2]; int cc[2];
    #pragma unroll
    for (int t = 0; t < 2; ++t) {
        const int c = t * 64 + lane;
        int ii = -1, jj = 0, off = 0;
        #pragma unroll
        for (int i = 0; i < 32; ++i) {
            const int cnt = 32 / (i + 1);
            const bool in = (c >= off) && (c < off + cnt);
            ii = in ? i : ii;
            jj = in ? c - off : jj;
            off += cnt;
        }
        if (ii >= 0) { cv[t] = ts[0][ii] + ts[1][jj]; cc[t] = ii * 32 + jj; }
        else         { cv[t] = -INFINITY;             cc[t] = 0x7fffffff;  }
    }

    unsigned used2 = 0;
    float mval = 0.f, myval = -INFINITY;
    int mycombo = 0;
    for (int it = 0; it < KNN; ++it) {
        float bv = -INFINITY; int bc = 0x7fffffff;
        #pragma unroll
        for (int t = 0; t < 2; ++t) {
            const bool live = !((used2 >> t) & 1u);
            const bool better = live &&
                (cv[t] > bv || (cv[t] == bv && cc[t] < bc));
            bv = better ? cv[t] : bv;
            bc = better ? cc[t] : bc;
        }
        float m = bv;
        #pragma unroll
        for (int off = 32; off; off >>= 1) m = fmaxf(m, __shfl_xor(m, off));
        const unsigned long long bal = __ballot(bv == m);
        int combo;
        if (__popcll(bal) == 1) {
            combo = __shfl(bc, (int)(__ffsll(bal) - 1));
        } else {
            unsigned cm = (bv == m) ? (unsigned)bc : 0xffffffffu;
            #pragma unroll
            for (int off = 32; off; off >>= 1) cm = min(cm, __shfl_xor(cm, off));
            combo = (int)cm;
        }
        if (it == 0) mval = m;
        if (lane == it) { myval = m; mycombo = combo; }
        #pragma unroll
        for (int t = 0; t < 2; ++t)
            if (cc[t] == combo) used2 |= 1u << t;
    }

    const float ew = (lane < KNN) ? expf(myval - mval) : 0.f;
    float ssum = ew;
    #pragma unroll
    for (int off = 32; off; off >>= 1) ssum += __shfl_xor(ssum, off);
    if (lane < KNN) {
        const int i1 = ti[0][mycombo >> 5];
        const int i2 = ti[1][mycombo & 31];
        w_out[(size_t)nh * KNN + lane] = ew / ssum;
        idx_out[(size_t)nh * KNN + lane] = i1 * NKEYS + i2;
    }
}

// =================== small-tile f32 NT GEMM: 64x64 (R4-proven) =============
__global__ __launch_bounds__(256)
void gemm_nt(const float* __restrict__ A, int lda,
             const float* __restrict__ B, int ldb,
             float* __restrict__ C, int ldc,
             const float* __restrict__ bias, int K)
{
    __shared__ __align__(16) float as[16][68];
    __shared__ __align__(16) float bs[16][68];
    const int tid = threadIdx.x;
    const int tx = tid & 15, ty = tid >> 4;
    const int m0 = blockIdx.y * 64, n0 = blockIdx.x * 64;
    const int lrow = tid >> 2;
    const int lk4  = (tid & 3) << 2;
    const float* Ap = A + (size_t)(m0 + lrow) * lda + lk4;
    const float* Bp = B + (size_t)(n0 + lrow) * ldb + lk4;
    float acc[4][4] = {};

    float4 av = *(const float4*)(Ap);
    float4 bv = *(const float4*)(Bp);
    for (int k0 = 0; k0 < K; k0 += 16) {
        __syncthreads();
        as[lk4 + 0][lrow] = av.x; as[lk4 + 1][lrow] = av.y;
        as[lk4 + 2][lrow] = av.z; as[lk4 + 3][lrow] = av.w;
        bs[lk4 + 0][lrow] = bv.x; bs[lk4 + 1][lrow] = bv.y;
        bs[lk4 + 2][lrow] = bv.z; bs[lk4 + 3][lrow] = bv.w;
        __syncthreads();
        if (k0 + 16 < K) {
            av = *(const float4*)(Ap + k0 + 16);
            bv = *(const float4*)(Bp + k0 + 16);
        }
        #pragma unroll
        for (int kk = 0; kk < 16; ++kk) {
            const float4 a = *(const float4*)&as[kk][ty << 2];
            const float4 b = *(const float4*)&bs[kk][tx << 2];
            const float ar[4] = {a.x, a.y, a.z, a.w};
            const float br[4] = {b.x, b.y, b.z, b.w};
            #pragma unroll
            for (int i = 0; i < 4; ++i)
                #pragma unroll
                for (int j = 0; j < 4; ++j)
                    acc[i][j] = fmaf(ar[i], br[j], acc[i][j]);
        }
    }

    float4 bb = {0.f, 0.f, 0.f, 0.f};
    if (bias) bb = *(const float4*)(bias + n0 + (tx << 2));
    #pragma unroll
    for (int i = 0; i < 4; ++i) {
        float4 o;
        o.x = acc[i][0] + bb.x; o.y = acc[i][1] + bb.y;
        o.z = acc[i][2] + bb.z; o.w = acc[i][3] + bb.w;
        *(float4*)(C + (size_t)(m0 + (ty << 2) + i) * ldc + n0 + (tx << 2)) = o;
    }
}

// =================== weighted embedding-bag gather + gate ==================
__global__ __launch_bounds__(256)
void gather_kernel(const float* __restrict__ values,
                   const float* __restrict__ w, const int* __restrict__ idx,
                   const float* __restrict__ gate, float* __restrict__ out0)
{
    const int n = blockIdx.x;
    const int t = threadIdx.x;
    __shared__ float sw[HEADS * KNN];
    __shared__ int   sidx[HEADS * KNN];
    if (t < HEADS * KNN) {
        sw[t]   = w[(size_t)n * HEADS * KNN + t];
        sidx[t] = idx[(size_t)n * HEADS * KNN + t];
    }
    __syncthreads();
    const int d0 = t * 2;
    float2 acc = {0.f, 0.f};
    #pragma unroll 8
    for (int k = 0; k < HEADS * KNN; ++k) {
        const float2 v = *(const float2*)(values + (size_t)sidx[k] * DOUT + d0);
        const float ww = sw[k];
        acc.x = fmaf(ww, v.x, acc.x);
        acc.y = fmaf(ww, v.y, acc.y);
    }
    const float2 g = *(const float2*)(gate + (size_t)n * DOUT + d0);
    acc.x *= g.x;
    acc.y *= g.y;
    *(float2*)(out0 + (size_t)n * DOUT + d0) = acc;
}

}  // namespace

extern "C" void kernel_launch(void* const* d_in, const int* in_sizes, int n_in,
                              void* d_out, int out_size, void* d_ws, size_t ws_size,
                              hipStream_t stream)
{
    const float* x      = (const float*)d_in[0];
    const float* Wq     = (const float*)d_in[1];
    const float* bq     = (const float*)d_in[2];
    const float* keys   = (const float*)d_in[3];
    const float* values = (const float*)d_in[4];
    const float* Wsw    = (const float*)d_in[5];
    const float* bsw    = (const float*)d_in[6];
    const float* Wv     = (const float*)d_in[7];
    const float* bv     = (const float*)d_in[8];
    float* out = (float*)d_out;

    // ws: q 16MB | qb 8MB | kb 1MB | s 32MB | wsc 1MB | idx 1MB | gate 4MB | out0 4MB
    float*          q    = (float*)d_ws;
    unsigned short* qb   = (unsigned short*)(q + (size_t)NROWS * HEADS * KDIM);
    unsigned short* kb   = qb + (size_t)NROWS * HEADS * KDIM;
    float*          s    = (float*)(kb + (size_t)8 * NKEYS * HALFD);
    float*          wsc  = s + (size_t)NROWS * HEADS * 2 * NKEYS;
    int*            idxb = (int*)(wsc + (size_t)NROWS * HEADS * KNN);
    float*          gate = (float*)(idxb + (size_t)NROWS * HEADS * KNN);
    float*          out0 = gate + (size_t)NROWS * DOUT;

    const dim3 blk(256);

    // 1) keys -> bf16  (independent)
    convert_keys<<<dim3(8 * NKEYS * HALFD / 1024), blk, 0, stream>>>(keys, kb);

    // 2) q = x@Wq^T + bq (f32 + bf16)  |  gate = silu(x@Wsw^T + bsw)
    qgate_gemm<<<dim3(32, 16, 2), blk, 0, stream>>>(
        x, Wq, bq, Wsw, bsw, q, qb, gate);

    // 3) approx scores via bf16 MFMA
    score_mfma<<<dim3(32, 8, 8), blk, 0, stream>>>(qb, kb, s);

    // 4) top-40 approx -> exact rescore -> exact two-stage top-32 + softmax
    topk_kernel<<<dim3(NROWS * HEADS), dim3(64), 0, stream>>>(
        s, q, keys, wsc, idxb);

    // 5) out0 = (sum_k w*values[idx]) * gate
    gather_kernel<<<dim3(NROWS), blk, 0, stream>>>(values, wsc, idxb, gate, out0);

    // 6) out = out0 @ Wv^T + bv
    gemm_nt<<<dim3(8, 32), blk, 0, stream>>>(
        out0, DOUT, Wv, DOUT, out, DOUT, bv, DOUT);
}

// Round 7
// 457.075 us; speedup vs baseline: 1.0465x; 1.0465x over previous
//
#include <hip/hip_runtime.h>
#include <math.h>

namespace {

constexpr int NROWS = 2048;   // B*T
constexpr int DIN   = 512;
constexpr int DOUT  = 512;
constexpr int HEADS = 4;
constexpr int KDIM  = 512;
constexpr int HALFD = 256;
constexpr int NKEYS = 512;
constexpr int KNN   = 32;

typedef short bf16x8 __attribute__((ext_vector_type(8)));
typedef float f32x4  __attribute__((ext_vector_type(4)));

__device__ inline unsigned short f2bf(float f) {   // round-to-nearest-even
    unsigned u = __float_as_uint(f);
    unsigned r = u + 0x7FFFu + ((u >> 16) & 1u);
    return (unsigned short)(r >> 16);
}
__device__ inline float bf2f(unsigned short h) {
    return __uint_as_float((unsigned)h << 16);
}
__device__ inline unsigned fmap(float f) {
    unsigned u = __float_as_uint(f);
    return (u & 0x80000000u) ? ~u : (u | 0x80000000u);
}
__device__ inline float funmap(unsigned m) {
    unsigned u = (m & 0x80000000u) ? (m & 0x7FFFFFFFu) : ~m;
    return __uint_as_float(u);
}
__device__ inline unsigned long long shflxor64(unsigned long long x, int m) {
    unsigned lo = (unsigned)x, hi = (unsigned)(x >> 32);
    lo = __shfl_xor(lo, m);
    hi = __shfl_xor(hi, m);
    return ((unsigned long long)hi << 32) | lo;
}

// =================== split f32 -> bf16 hi + bf16 lo ========================
// z=0: x (1M elems)   z=1: Wsw (256K)   z=2: keys (1M)
__global__ __launch_bounds__(256)
void split3(const float* __restrict__ x, const float* __restrict__ wsw,
            const float* __restrict__ keys,
            unsigned short* __restrict__ xh, unsigned short* __restrict__ xl,
            unsigned short* __restrict__ wh, unsigned short* __restrict__ wl,
            unsigned short* __restrict__ kh, unsigned short* __restrict__ kl)
{
    const int z = blockIdx.z;
    const float* src = (z == 0) ? x : (z == 1) ? wsw : keys;
    unsigned short* ph = (z == 0) ? xh : (z == 1) ? wh : kh;
    unsigned short* pl = (z == 0) ? xl : (z == 1) ? wl : kl;
    const int n = (z == 1) ? 262144 : 1048576;
    const int i = (blockIdx.x * 256 + threadIdx.x) * 4;
    if (i >= n) return;
    const float4 v = *(const float4*)(src + i);
    ushort4 oh, ol;
    oh.x = f2bf(v.x); ol.x = f2bf(v.x - bf2f(oh.x));
    oh.y = f2bf(v.y); ol.y = f2bf(v.y - bf2f(oh.y));
    oh.z = f2bf(v.z); ol.z = f2bf(v.z - bf2f(oh.z));
    oh.w = f2bf(v.w); ol.w = f2bf(v.w - bf2f(oh.w));
    *(ushort4*)(ph + i) = oh;
    *(ushort4*)(pl + i) = ol;
}

// =================== q GEMM: 128x64 f32 (R4-proven) + hi/lo dual-store =====
__global__ __launch_bounds__(256)
void gemm_q(const float* __restrict__ A, const float* __restrict__ B,
            float* __restrict__ C, unsigned short* __restrict__ Ch,
            unsigned short* __restrict__ Cl, const float* __restrict__ bias)
{
    constexpr int lda = DIN, ldb = DIN, ldc = HEADS * KDIM, K = DIN;
    const int m0 = blockIdx.y * 128, n0 = blockIdx.x * 64;
    __shared__ __align__(16) float as[16][132];
    __shared__ __align__(16) float bs[16][68];
    const int tid = threadIdx.x;
    const int tx = tid & 15, ty = tid >> 4;
    const int lrA = tid >> 1, lkA = (tid & 1) << 3;
    const int lrB = tid >> 2, lkB = (tid & 3) << 2;
    const float* Ap = A + (size_t)(m0 + lrA) * lda + lkA;
    const float* Bp = B + (size_t)(n0 + lrB) * ldb + lkB;
    float acc[8][4] = {};

    float4 a0 = *(const float4*)(Ap);
    float4 a1 = *(const float4*)(Ap + 4);
    float4 b0 = *(const float4*)(Bp);
    for (int k0 = 0; k0 < K; k0 += 16) {
        __syncthreads();
        as[lkA + 0][lrA] = a0.x; as[lkA + 1][lrA] = a0.y;
        as[lkA + 2][lrA] = a0.z; as[lkA + 3][lrA] = a0.w;
        as[lkA + 4][lrA] = a1.x; as[lkA + 5][lrA] = a1.y;
        as[lkA + 6][lrA] = a1.z; as[lkA + 7][lrA] = a1.w;
        bs[lkB + 0][lrB] = b0.x; bs[lkB + 1][lrB] = b0.y;
        bs[lkB + 2][lrB] = b0.z; bs[lkB + 3][lrB] = b0.w;
        __syncthreads();
        if (k0 + 16 < K) {
            a0 = *(const float4*)(Ap + k0 + 16);
            a1 = *(const float4*)(Ap + k0 + 20);
            b0 = *(const float4*)(Bp + k0 + 16);
        }
        #pragma unroll
        for (int kk = 0; kk < 16; ++kk) {
            const float4 a0v = *(const float4*)&as[kk][ty << 3];
            const float4 a1v = *(const float4*)&as[kk][(ty << 3) + 4];
            const float4 bv  = *(const float4*)&bs[kk][tx << 2];
            const float ar[8] = {a0v.x, a0v.y, a0v.z, a0v.w,
                                 a1v.x, a1v.y, a1v.z, a1v.w};
            const float br[4] = {bv.x, bv.y, bv.z, bv.w};
            #pragma unroll
            for (int i = 0; i < 8; ++i)
                #pragma unroll
                for (int j = 0; j < 4; ++j)
                    acc[i][j] = fmaf(ar[i], br[j], acc[i][j]);
        }
    }

    const float4 bb = *(const float4*)(bias + n0 + (tx << 2));
    #pragma unroll
    for (int i = 0; i < 8; ++i) {
        float4 o;
        o.x = acc[i][0] + bb.x; o.y = acc[i][1] + bb.y;
        o.z = acc[i][2] + bb.z; o.w = acc[i][3] + bb.w;
        const size_t off = (size_t)(m0 + (ty << 3) + i) * ldc + n0 + (tx << 2);
        *(float4*)(C + off) = o;
        ushort4 oh, ol;
        oh.x = f2bf(o.x); ol.x = f2bf(o.x - bf2f(oh.x));
        oh.y = f2bf(o.y); ol.y = f2bf(o.y - bf2f(oh.y));
        oh.z = f2bf(o.z); ol.z = f2bf(o.z - bf2f(oh.z));
        oh.w = f2bf(o.w); ol.w = f2bf(o.w - bf2f(oh.w));
        *(ushort4*)(Ch + off) = oh;
        *(ushort4*)(Cl + off) = ol;
    }
}

// =================== 3-term split-bf16 MFMA GEMM ===========================
// z<8: s_z = q_z @ keys_z^T (K=256).  z==8: gate = silu(x@Wsw^T + bsw) (K=512).
// acc = Ah*Bh + Ah*Bl + Al*Bh (lo*lo dropped, rel err ~2^-18).
// Wave tile 16(M)x64(N).  C-map: col=lane&15, row=(lane>>4)*4+r [R6-verified].
__global__ __launch_bounds__(256)
void mfma3(const unsigned short* __restrict__ qh, const unsigned short* __restrict__ ql,
           const unsigned short* __restrict__ kh, const unsigned short* __restrict__ kl,
           const unsigned short* __restrict__ xh, const unsigned short* __restrict__ xl,
           const unsigned short* __restrict__ wh, const unsigned short* __restrict__ wl,
           const float* __restrict__ bsw, float* __restrict__ s,
           float* __restrict__ gate)
{
    const int z = blockIdx.z;
    const int wave = threadIdx.x >> 6;
    const int lane = threadIdx.x & 63;
    const int r16 = lane & 15, kc = lane >> 4;
    const int m0 = blockIdx.x * 64 + wave * 16;
    const int n0 = blockIdx.y * 64;

    const unsigned short *A0, *A1, *B0, *B1;
    int K, ldc, coff;
    float* C;
    if (z < 8) {
        const size_t aoff = (size_t)(m0 + r16) * (HEADS * KDIM)
                          + (z >> 1) * KDIM + (z & 1) * HALFD + kc * 8;
        const size_t boff = ((size_t)z * NKEYS + n0 + r16) * HALFD + kc * 8;
        A0 = qh + aoff; A1 = ql + aoff;
        B0 = kh + boff; B1 = kl + boff;
        K = HALFD; C = s; ldc = HEADS * 2 * NKEYS; coff = z * NKEYS;
    } else {
        const size_t aoff = (size_t)(m0 + r16) * DIN + kc * 8;
        const size_t boff = (size_t)(n0 + r16) * DIN + kc * 8;
        A0 = xh + aoff; A1 = xl + aoff;
        B0 = wh + boff; B1 = wl + boff;
        K = DIN; C = gate; ldc = DOUT; coff = 0;
    }

    f32x4 acc[4] = {{0,0,0,0},{0,0,0,0},{0,0,0,0},{0,0,0,0}};
    const int nkk = K >> 5;
    #pragma unroll
    for (int pair = 0; pair < 3; ++pair) {
        const unsigned short* ap = (pair == 2) ? A1 : A0;
        const unsigned short* bp = (pair == 1) ? B1 : B0;
        for (int kk = 0; kk < nkk; ++kk) {
            const bf16x8 a = *(const bf16x8*)(ap + kk * 32);
            #pragma unroll
            for (int t = 0; t < 4; ++t) {
                const bf16x8 b = *(const bf16x8*)(bp + (size_t)t * 16 * K + kk * 32);
                acc[t] = __builtin_amdgcn_mfma_f32_16x16x32_bf16(a, b, acc[t], 0, 0, 0);
            }
        }
    }

    #pragma unroll
    for (int t = 0; t < 4; ++t)
        #pragma unroll
        for (int r = 0; r < 4; ++r) {
            float v = acc[t][r];
            if (z == 8) {
                v += bsw[n0 + t * 16 + r16];
                v = v / (1.f + expf(-v));
            }
            C[(size_t)(m0 + kc * 4 + r) * ldc + coff + n0 + t * 16 + r16] = v;
        }
}

// =================== topk v2: tau-select -> exact rescore -> exact top-32 ==
// One 64-lane wave per (n,h); 32-lane subgroup per half.
// Candidate window [40,56] on approx scores (sigma~3e-6 << gap ~0.02: safe).
// Rescore = exact ascending-k f32 fmaf chain == R2/R4 score GEMM (bitwise).
__global__ __launch_bounds__(64)
void topk2(const float* __restrict__ s, const float* __restrict__ q,
           const float* __restrict__ keys,
           float* __restrict__ w_out, int* __restrict__ idx_out)
{
    const int nh   = blockIdx.x;
    const int n    = nh >> 2;
    const int h    = nh & 3;
    const int lane = threadIdx.x;
    const int sub  = lane >> 5;
    const int sl   = lane & 31;
    __shared__ float qlds[KDIM];
    __shared__ int   cl[2][64];
    __shared__ unsigned long long pkl[2][64];
    __shared__ int   csh[2];
    __shared__ float ts[2][KNN];
    __shared__ int   ti[2][KNN];

    // q row (f32) to LDS
    const float* qrow = q + (size_t)n * (HEADS * KDIM) + h * KDIM;
    #pragma unroll
    for (int j = 0; j < 8; ++j) qlds[j * 64 + lane] = qrow[j * 64 + lane];

    // ---- approx scores -> sortable ints ----
    const float* sb = s + (size_t)nh * (2 * NKEYS) + sub * NKEYS;
    unsigned u[16];
    #pragma unroll
    for (int i = 0; i < 16; ++i) u[i] = fmap(sb[i * 32 + sl]);

    // ---- bisect tau: count(u >= tau) in [40,56] (per sub) ----
    unsigned lo = 0, hi = 0xFFFFFFFFu, tau = 0;
    bool found = false;
    for (int iter = 0; iter < 30; ++iter) {
        if (__all(found)) break;
        const unsigned mid = lo + ((hi - lo) >> 1);
        int c = 0;
        #pragma unroll
        for (int i = 0; i < 16; ++i) c += (u[i] >= mid) ? 1 : 0;
        #pragma unroll
        for (int off = 1; off <= 16; off <<= 1) c += __shfl_xor(c, off);
        if (!found) {
            if (c >= 40 && c <= 56) { tau = mid; found = true; }
            else if (c > 56) lo = mid + 1;
            else hi = mid - 1;
        }
    }
    if (!found) tau = lo;   // pathological-tie fallback (count capped below)

    // ---- ballot-compact candidates (element ids) into LDS ----
    unsigned msk = 0;
    #pragma unroll
    for (int i = 0; i < 16; ++i) msk |= (u[i] >= tau ? 1u : 0u) << i;
    int mc = __popc(msk);
    int pfx = mc;
    #pragma unroll
    for (int d = 1; d <= 16; d <<= 1) {
        const int t = __shfl_up(pfx, d);
        if (sl >= d) pfx += t;
    }
    int slot = pfx - mc;
    #pragma unroll
    for (int i = 0; i < 16; ++i)
        if ((msk >> i) & 1u) {
            if (slot < 64) cl[sub][slot] = (i << 5) | sl;
            ++slot;
        }
    if (sl == 31) csh[sub] = (pfx < 64) ? pfx : 64;
    __syncthreads();

    // ---- exact rescore: one candidate per lane, per half ----
    #pragma unroll
    for (int p = 0; p < 2; ++p) {
        const int cnt = csh[p];
        const int ci = cl[p][lane < cnt ? lane : cnt - 1];
        const float* kr = keys + ((size_t)(h * 2 + p) * NKEYS + ci) * HALFD;
        const float* qh_ = qlds + p * HALFD;
        float a = 0.f;
        #pragma unroll
        for (int kb = 0; kb < 4; ++kb) {
            float4 rr[16];
            #pragma unroll
            for (int j = 0; j < 16; ++j)
                rr[j] = *(const float4*)(kr + kb * 64 + j * 4);
            #pragma unroll
            for (int j = 0; j < 16; ++j) {
                a = fmaf(qh_[kb * 64 + j * 4 + 0], rr[j].x, a);
                a = fmaf(qh_[kb * 64 + j * 4 + 1], rr[j].y, a);
                a = fmaf(qh_[kb * 64 + j * 4 + 2], rr[j].z, a);
                a = fmaf(qh_[kb * 64 + j * 4 + 3], rr[j].w, a);
            }
        }
        pkl[p][lane] = (lane < cnt)
            ? (((unsigned long long)fmap(a) << 32) | (unsigned)(~ci))
            : ((unsigned long long)fmap(-INFINITY) << 32);
    }
    __syncthreads();

    // ---- exact top-32 of <=64 per half (value desc, index asc) ----
    unsigned long long pk0 = pkl[sub][sl], pk1 = pkl[sub][sl + 32];
    for (int it = 0; it < KNN; ++it) {
        unsigned long long best = pk0 > pk1 ? pk0 : pk1;
        #pragma unroll
        for (int off = 16; off; off >>= 1) {
            const unsigned long long o = shflxor64(best, off);
            if (o > best) best = o;
        }
        if (sl == 0) {
            ts[sub][it] = funmap((unsigned)(best >> 32));
            ti[sub][it] = (int)(~(unsigned)best) & (NKEYS - 1);
        }
        if (pk0 == best) pk0 = 0ull;
        if (pk1 == best) pk1 = 0ull;
    }
    __syncthreads();

    // ---- stage 2: top-32 of the 119 pruned cartesian sums (R2-verified) ----
    float cv[2]; int cc[2];
    #pragma unroll
    for (int t = 0; t < 2; ++t) {
        const int c = t * 64 + lane;
        int ii = -1, jj = 0, off = 0;
        #pragma unroll
        for (int i = 0; i < 32; ++i) {
            const int cnt = 32 / (i + 1);
            const bool in = (c >= off) && (c < off + cnt);
            ii = in ? i : ii;
            jj = in ? c - off : jj;
            off += cnt;
        }
        if (ii >= 0) { cv[t] = ts[0][ii] + ts[1][jj]; cc[t] = ii * 32 + jj; }
        else         { cv[t] = -INFINITY;             cc[t] = 0x7fffffff;  }
    }

    unsigned used2 = 0;
    float mval = 0.f, myval = -INFINITY;
    int mycombo = 0;
    for (int it = 0; it < KNN; ++it) {
        float bv = -INFINITY; int bc = 0x7fffffff;
        #pragma unroll
        for (int t = 0; t < 2; ++t) {
            const bool live = !((used2 >> t) & 1u);
            const bool better = live &&
                (cv[t] > bv || (cv[t] == bv && cc[t] < bc));
            bv = better ? cv[t] : bv;
            bc = better ? cc[t] : bc;
        }
        float m = bv;
        #pragma unroll
        for (int off = 32; off; off >>= 1) m = fmaxf(m, __shfl_xor(m, off));
        const unsigned long long bal = __ballot(bv == m);
        int combo;
        if (__popcll(bal) == 1) {
            combo = __shfl(bc, (int)(__ffsll(bal) - 1));
        } else {
            unsigned cm = (bv == m) ? (unsigned)bc : 0xffffffffu;
            #pragma unroll
            for (int off = 32; off; off >>= 1) cm = min(cm, __shfl_xor(cm, off));
            combo = (int)cm;
        }
        if (it == 0) mval = m;
        if (lane == it) { myval = m; mycombo = combo; }
        #pragma unroll
        for (int t = 0; t < 2; ++t)
            if (cc[t] == combo) used2 |= 1u << t;
    }

    const float ew = (lane < KNN) ? expf(myval - mval) : 0.f;
    float ssum = ew;
    #pragma unroll
    for (int off = 32; off; off >>= 1) ssum += __shfl_xor(ssum, off);
    if (lane < KNN) {
        const int i1 = ti[0][mycombo >> 5];
        const int i2 = ti[1][mycombo & 31];
        w_out[(size_t)nh * KNN + lane] = ew / ssum;
        idx_out[(size_t)nh * KNN + lane] = i1 * NKEYS + i2;
    }
}

// =================== small-tile f32 NT GEMM: 64x64 (R4-proven) =============
__global__ __launch_bounds__(256)
void gemm_nt(const float* __restrict__ A, int lda,
             const float* __restrict__ B, int ldb,
             float* __restrict__ C, int ldc,
             const float* __restrict__ bias, int K)
{
    __shared__ __align__(16) float as[16][68];
    __shared__ __align__(16) float bs[16][68];
    const int tid = threadIdx.x;
    const int tx = tid & 15, ty = tid >> 4;
    const int m0 = blockIdx.y * 64, n0 = blockIdx.x * 64;
    const int lrow = tid >> 2;
    const int lk4  = (tid & 3) << 2;
    const float* Ap = A + (size_t)(m0 + lrow) * lda + lk4;
    const float* Bp = B + (size_t)(n0 + lrow) * ldb + lk4;
    float acc[4][4] = {};

    float4 av = *(const float4*)(Ap);
    float4 bv = *(const float4*)(Bp);
    for (int k0 = 0; k0 < K; k0 += 16) {
        __syncthreads();
        as[lk4 + 0][lrow] = av.x; as[lk4 + 1][lrow] = av.y;
        as[lk4 + 2][lrow] = av.z; as[lk4 + 3][lrow] = av.w;
        bs[lk4 + 0][lrow] = bv.x; bs[lk4 + 1][lrow] = bv.y;
        bs[lk4 + 2][lrow] = bv.z; bs[lk4 + 3][lrow] = bv.w;
        __syncthreads();
        if (k0 + 16 < K) {
            av = *(const float4*)(Ap + k0 + 16);
            bv = *(const float4*)(Bp + k0 + 16);
        }
        #pragma unroll
        for (int kk = 0; kk < 16; ++kk) {
            const float4 a = *(const float4*)&as[kk][ty << 2];
            const float4 b = *(const float4*)&bs[kk][tx << 2];
            const float ar[4] = {a.x, a.y, a.z, a.w};
            const float br[4] = {b.x, b.y, b.z, b.w};
            #pragma unroll
            for (int i = 0; i < 4; ++i)
                #pragma unroll
                for (int j = 0; j < 4; ++j)
                    acc[i][j] = fmaf(ar[i], br[j], acc[i][j]);
        }
    }

    float4 bb = {0.f, 0.f, 0.f, 0.f};
    if (bias) bb = *(const float4*)(bias + n0 + (tx << 2));
    #pragma unroll
    for (int i = 0; i < 4; ++i) {
        float4 o;
        o.x = acc[i][0] + bb.x; o.y = acc[i][1] + bb.y;
        o.z = acc[i][2] + bb.z; o.w = acc[i][3] + bb.w;
        *(float4*)(C + (size_t)(m0 + (ty << 2) + i) * ldc + n0 + (tx << 2)) = o;
    }
}

// =================== weighted embedding-bag gather + gate ==================
__global__ __launch_bounds__(256)
void gather_kernel(const float* __restrict__ values,
                   const float* __restrict__ w, const int* __restrict__ idx,
                   const float* __restrict__ gate, float* __restrict__ out0)
{
    const int n = blockIdx.x;
    const int t = threadIdx.x;
    __shared__ float sw[HEADS * KNN];
    __shared__ int   sidx[HEADS * KNN];
    if (t < HEADS * KNN) {
        sw[t]   = w[(size_t)n * HEADS * KNN + t];
        sidx[t] = idx[(size_t)n * HEADS * KNN + t];
    }
    __syncthreads();
    const int d0 = t * 2;
    float2 acc = {0.f, 0.f};
    #pragma unroll 8
    for (int k = 0; k < HEADS * KNN; ++k) {
        const float2 v = *(const float2*)(values + (size_t)sidx[k] * DOUT + d0);
        const float ww = sw[k];
        acc.x = fmaf(ww, v.x, acc.x);
        acc.y = fmaf(ww, v.y, acc.y);
    }
    const float2 g = *(const float2*)(gate + (size_t)n * DOUT + d0);
    acc.x *= g.x;
    acc.y *= g.y;
    *(float2*)(out0 + (size_t)n * DOUT + d0) = acc;
}

}  // namespace

extern "C" void kernel_launch(void* const* d_in, const int* in_sizes, int n_in,
                              void* d_out, int out_size, void* d_ws, size_t ws_size,
                              hipStream_t stream)
{
    const float* x      = (const float*)d_in[0];
    const float* Wq     = (const float*)d_in[1];
    const float* bq     = (const float*)d_in[2];
    const float* keys   = (const float*)d_in[3];
    const float* values = (const float*)d_in[4];
    const float* Wsw    = (const float*)d_in[5];
    const float* bsw    = (const float*)d_in[6];
    const float* Wv     = (const float*)d_in[7];
    const float* bv     = (const float*)d_in[8];
    float* out = (float*)d_out;

    // workspace layout
    float*          q    = (float*)d_ws;                                   // 16MB
    unsigned short* qh   = (unsigned short*)(q + (size_t)NROWS * HEADS * KDIM);  // 8MB
    unsigned short* ql   = qh + (size_t)NROWS * HEADS * KDIM;              // 8MB
    float*          s    = (float*)(ql + (size_t)NROWS * HEADS * KDIM);    // 32MB
    unsigned short* xh   = (unsigned short*)(s + (size_t)NROWS * HEADS * 2 * NKEYS);
    unsigned short* xl   = xh + (size_t)NROWS * DIN;
    unsigned short* wh   = xl + (size_t)NROWS * DIN;
    unsigned short* wl   = wh + (size_t)DOUT * DIN;
    unsigned short* kh   = wl + (size_t)DOUT * DIN;
    unsigned short* kl   = kh + (size_t)8 * NKEYS * HALFD;
    float*          wsc  = (float*)(kl + (size_t)8 * NKEYS * HALFD);
    int*            idxb = (int*)(wsc + (size_t)NROWS * HEADS * KNN);
    float*          gate = (float*)(idxb + (size_t)NROWS * HEADS * KNN);
    float*          out0 = gate + (size_t)NROWS * DOUT;

    const dim3 blk(256);

    // 1) split x / Wsw / keys into bf16 hi+lo
    split3<<<dim3(1024, 1, 3), blk, 0, stream>>>(
        x, Wsw, keys, xh, xl, wh, wl, kh, kl);

    // 2) q = x @ Wq^T + bq  (exact f32, R4 chain) + hi/lo dual-store
    gemm_q<<<dim3(32, 16), blk, 0, stream>>>(x, Wq, q, qh, ql, bq);

    // 3) approx scores (z<8, split-bf16 MFMA) + gate (z==8, silu)
    mfma3<<<dim3(32, 8, 9), blk, 0, stream>>>(
        qh, ql, kh, kl, xh, xl, wh, wl, bsw, s, gate);

    // 4) tau-select -> exact rescore -> exact two-stage top-32 + softmax
    topk2<<<dim3(NROWS * HEADS), dim3(64), 0, stream>>>(
        s, q, keys, wsc, idxb);

    // 5) out0 = (sum_k w*values[idx]) * gate
    gather_kernel<<<dim3(NROWS), blk, 0, stream>>>(values, wsc, idxb, gate, out0);

    // 6) out = out0 @ Wv^T + bv
    gemm_nt<<<dim3(8, 32), blk, 0, stream>>>(
        out0, DOUT, Wv, DOUT, out, DOUT, bv, DOUT);
}

// Round 8
// 348.167 us; speedup vs baseline: 1.3738x; 1.3128x over previous
//
#include <hip/hip_runtime.h>
#include <math.h>

namespace {

constexpr int NROWS = 2048;   // B*T
constexpr int DIN   = 512;
constexpr int DOUT  = 512;
constexpr int HEADS = 4;
constexpr int KDIM  = 512;
constexpr int HALFD = 256;
constexpr int NKEYS = 512;
constexpr int KNN   = 32;

typedef short bf16x8 __attribute__((ext_vector_type(8)));
typedef float f32x4  __attribute__((ext_vector_type(4)));

__device__ inline unsigned short f2bf(float f) {   // round-to-nearest-even
    unsigned u = __float_as_uint(f);
    unsigned r = u + 0x7FFFu + ((u >> 16) & 1u);
    return (unsigned short)(r >> 16);
}
__device__ inline float bf2f(unsigned short h) {
    return __uint_as_float((unsigned)h << 16);
}
__device__ inline unsigned fmap(float f) {
    unsigned u = __float_as_uint(f);
    return (u & 0x80000000u) ? ~u : (u | 0x80000000u);
}
__device__ inline float funmap(unsigned m) {
    unsigned u = (m & 0x80000000u) ? (m & 0x7FFFFFFFu) : ~m;
    return __uint_as_float(u);
}
__device__ inline unsigned long long shflxor64(unsigned long long x, int m) {
    unsigned lo = (unsigned)x, hi = (unsigned)(x >> 32);
    lo = __shfl_xor(lo, m);
    hi = __shfl_xor(hi, m);
    return ((unsigned long long)hi << 32) | lo;
}

// =================== split: x->hi/lo, Wsw->hi/lo, keys->hi =================
__global__ __launch_bounds__(256)
void split3(const float* __restrict__ x, const float* __restrict__ wsw,
            const float* __restrict__ keys,
            unsigned short* __restrict__ xh, unsigned short* __restrict__ xl,
            unsigned short* __restrict__ wh, unsigned short* __restrict__ wl,
            unsigned short* __restrict__ kh)
{
    const int z = blockIdx.z;
    const int i = (blockIdx.x * 256 + threadIdx.x) * 4;
    if (z == 2) {                      // keys -> hi only
        if (i >= 1048576) return;
        const float4 v = *(const float4*)(keys + i);
        ushort4 oh;
        oh.x = f2bf(v.x); oh.y = f2bf(v.y); oh.z = f2bf(v.z); oh.w = f2bf(v.w);
        *(ushort4*)(kh + i) = oh;
        return;
    }
    const float* src = (z == 0) ? x : wsw;
    unsigned short* ph = (z == 0) ? xh : wh;
    unsigned short* pl = (z == 0) ? xl : wl;
    const int n = (z == 1) ? 262144 : 1048576;
    if (i >= n) return;
    const float4 v = *(const float4*)(src + i);
    ushort4 oh, ol;
    oh.x = f2bf(v.x); ol.x = f2bf(v.x - bf2f(oh.x));
    oh.y = f2bf(v.y); ol.y = f2bf(v.y - bf2f(oh.y));
    oh.z = f2bf(v.z); ol.z = f2bf(v.z - bf2f(oh.z));
    oh.w = f2bf(v.w); ol.w = f2bf(v.w - bf2f(oh.w));
    *(ushort4*)(ph + i) = oh;
    *(ushort4*)(pl + i) = ol;
}

// =================== q GEMM: 128x128 tile, 8x8 micro, exact f32 chain ======
// C[m,n] = sum_k(asc) A[m,k]*B[n,k] + bias[n]; bit-identical chain to R4.
// Dual-stores f32 q and bf16-hi qh.
__global__ __launch_bounds__(256)
void gemm_q(const float* __restrict__ A, const float* __restrict__ B,
            float* __restrict__ C, unsigned short* __restrict__ Ch,
            const float* __restrict__ bias)
{
    constexpr int ldc = HEADS * KDIM;
    __shared__ __align__(16) float as[16][132];
    __shared__ __align__(16) float bs[16][132];
    const int tid = threadIdx.x;
    const int tx = tid & 15, ty = tid >> 4;
    const int m0 = blockIdx.y * 128, n0 = blockIdx.x * 128;
    const int lr = tid >> 1, lk = (tid & 1) << 3;
    const float* Ap = A + (size_t)(m0 + lr) * DIN + lk;
    const float* Bp = B + (size_t)(n0 + lr) * DIN + lk;
    float acc[8][8] = {};

    float4 a0 = *(const float4*)(Ap);
    float4 a1 = *(const float4*)(Ap + 4);
    float4 b0 = *(const float4*)(Bp);
    float4 b1 = *(const float4*)(Bp + 4);

    for (int k0 = 0; k0 < DIN; k0 += 16) {
        __syncthreads();
        as[lk + 0][lr] = a0.x; as[lk + 1][lr] = a0.y;
        as[lk + 2][lr] = a0.z; as[lk + 3][lr] = a0.w;
        as[lk + 4][lr] = a1.x; as[lk + 5][lr] = a1.y;
        as[lk + 6][lr] = a1.z; as[lk + 7][lr] = a1.w;
        bs[lk + 0][lr] = b0.x; bs[lk + 1][lr] = b0.y;
        bs[lk + 2][lr] = b0.z; bs[lk + 3][lr] = b0.w;
        bs[lk + 4][lr] = b1.x; bs[lk + 5][lr] = b1.y;
        bs[lk + 6][lr] = b1.z; bs[lk + 7][lr] = b1.w;
        __syncthreads();
        if (k0 + 16 < DIN) {
            a0 = *(const float4*)(Ap + k0 + 16);
            a1 = *(const float4*)(Ap + k0 + 20);
            b0 = *(const float4*)(Bp + k0 + 16);
            b1 = *(const float4*)(Bp + k0 + 20);
        }
        #pragma unroll
        for (int kk = 0; kk < 16; ++kk) {
            const float4 xa0 = *(const float4*)&as[kk][ty << 3];
            const float4 xa1 = *(const float4*)&as[kk][(ty << 3) + 4];
            const float4 xb0 = *(const float4*)&bs[kk][tx << 3];
            const float4 xb1 = *(const float4*)&bs[kk][(tx << 3) + 4];
            const float ar[8] = {xa0.x, xa0.y, xa0.z, xa0.w,
                                 xa1.x, xa1.y, xa1.z, xa1.w};
            const float br[8] = {xb0.x, xb0.y, xb0.z, xb0.w,
                                 xb1.x, xb1.y, xb1.z, xb1.w};
            #pragma unroll
            for (int i = 0; i < 8; ++i)
                #pragma unroll
                for (int j = 0; j < 8; ++j)
                    acc[i][j] = fmaf(ar[i], br[j], acc[i][j]);
        }
    }

    const float4 bb0 = *(const float4*)(bias + n0 + (tx << 3));
    const float4 bb1 = *(const float4*)(bias + n0 + (tx << 3) + 4);
    #pragma unroll
    for (int i = 0; i < 8; ++i) {
        float4 o0, o1;
        o0.x = acc[i][0] + bb0.x; o0.y = acc[i][1] + bb0.y;
        o0.z = acc[i][2] + bb0.z; o0.w = acc[i][3] + bb0.w;
        o1.x = acc[i][4] + bb1.x; o1.y = acc[i][5] + bb1.y;
        o1.z = acc[i][6] + bb1.z; o1.w = acc[i][7] + bb1.w;
        const size_t off = (size_t)(m0 + (ty << 3) + i) * ldc + n0 + (tx << 3);
        *(float4*)(C + off) = o0;
        *(float4*)(C + off + 4) = o1;
        ushort4 h0, h1;
        h0.x = f2bf(o0.x); h0.y = f2bf(o0.y); h0.z = f2bf(o0.z); h0.w = f2bf(o0.w);
        h1.x = f2bf(o1.x); h1.y = f2bf(o1.y); h1.z = f2bf(o1.z); h1.w = f2bf(o1.w);
        *(ushort4*)(Ch + off) = h0;
        *(ushort4*)(Ch + off + 4) = h1;
    }
}

// =================== LDS-staged bf16 MFMA: scores (z<8) + gate (z==8) ======
// Tile 128x128, BK=64, 4 waves (2x2), 16x16x32 MFMA.
// LDS row-major [row][64] bf16 with XOR swizzle byte ^= (row&7)<<4 (T2).
// z<8 : s_z = qh_z @ kh_z^T  (1 term, K=256)  [R6-verified margin safety]
// z==8: gate = silu(xh@wh^T + xh@wl^T + xl@wh^T + bsw)  (3 terms, K=512)
__global__ __launch_bounds__(256)
void mfma_sg(const unsigned short* __restrict__ qh,
             const unsigned short* __restrict__ kh,
             const unsigned short* __restrict__ xh, const unsigned short* __restrict__ xl,
             const unsigned short* __restrict__ wh, const unsigned short* __restrict__ wl,
             const float* __restrict__ bsw,
             float* __restrict__ s, float* __restrict__ gate)
{
    __shared__ __align__(16) unsigned short Al[128 * 64];
    __shared__ __align__(16) unsigned short Bl[128 * 64];
    const int tid  = threadIdx.x;
    const int wid  = tid >> 6, lane = tid & 63;
    const int r16  = lane & 15, kc = lane >> 4;
    const int wr   = wid >> 1, wc = wid & 1;
    const int z    = blockIdx.z;
    const int bx   = blockIdx.x, by = blockIdx.y;
    const int srow = tid >> 1;            // staging row 0..127
    const int skb  = (tid & 1) << 5;      // staging k-base 0/32
    const unsigned swzw = (unsigned)((srow & 7) << 4);

    f32x4 acc[4][4] = {};
    const int nterm = (z < 8) ? 1 : 3;

    for (int term = 0; term < nterm; ++term) {
        const unsigned short *Ag, *Bg;
        int K;
        if (z < 8) {
            Ag = qh + (size_t)(bx * 128 + srow) * (HEADS * KDIM)
               + (z >> 1) * KDIM + (z & 1) * HALFD + skb;
            Bg = kh + ((size_t)z * NKEYS + by * 128 + srow) * HALFD + skb;
            K = HALFD;
        } else {
            Ag = ((term == 2) ? xl : xh) + (size_t)(bx * 128 + srow) * DIN + skb;
            Bg = ((term == 1) ? wl : wh) + (size_t)(by * 128 + srow) * DIN + skb;
            K = DIN;
        }
        for (int k0 = 0; k0 < K; k0 += 64) {
            __syncthreads();
            #pragma unroll
            for (int j = 0; j < 4; ++j) {
                const uint4 va = *(const uint4*)(Ag + k0 + j * 8);
                const uint4 vb = *(const uint4*)(Bg + k0 + j * 8);
                const unsigned boff = (unsigned)(srow * 128 + (skb + j * 8) * 2) ^ swzw;
                *(uint4*)((char*)Al + boff) = va;
                *(uint4*)((char*)Bl + boff) = vb;
            }
            __syncthreads();
            #pragma unroll
            for (int ks = 0; ks < 2; ++ks) {
                bf16x8 af[4], bf[4];
                #pragma unroll
                for (int f = 0; f < 4; ++f) {
                    const int am = wr * 64 + f * 16 + r16;
                    af[f] = *(const bf16x8*)((const char*)Al +
                        ((unsigned)(am * 128 + ks * 64 + kc * 16) ^ ((am & 7) << 4)));
                    const int bn = wc * 64 + f * 16 + r16;
                    bf[f] = *(const bf16x8*)((const char*)Bl +
                        ((unsigned)(bn * 128 + ks * 64 + kc * 16) ^ ((bn & 7) << 4)));
                }
                #pragma unroll
                for (int fm = 0; fm < 4; ++fm)
                    #pragma unroll
                    for (int fn = 0; fn < 4; ++fn)
                        acc[fm][fn] = __builtin_amdgcn_mfma_f32_16x16x32_bf16(
                            af[fm], bf[fn], acc[fm][fn], 0, 0, 0);
            }
        }
    }

    #pragma unroll
    for (int fm = 0; fm < 4; ++fm) {
        const int row = bx * 128 + wr * 64 + fm * 16 + kc * 4;
        #pragma unroll
        for (int fn = 0; fn < 4; ++fn) {
            const int col = by * 128 + wc * 64 + fn * 16 + r16;
            #pragma unroll
            for (int r = 0; r < 4; ++r) {
                float v = acc[fm][fn][r];
                if (z < 8) {
                    s[(size_t)(row + r) * (HEADS * 2 * NKEYS) + z * NKEYS + col] = v;
                } else {
                    v += bsw[col];
                    v = v / (1.f + expf(-v));
                    gate[(size_t)(row + r) * DOUT + col] = v;
                }
            }
        }
    }
}

// =================== topk v2 (R7-proven): tau-select -> exact rescore ======
__global__ __launch_bounds__(64)
void topk2(const float* __restrict__ s, const float* __restrict__ q,
           const float* __restrict__ keys,
           float* __restrict__ w_out, int* __restrict__ idx_out)
{
    const int nh   = blockIdx.x;
    const int n    = nh >> 2;
    const int h    = nh & 3;
    const int lane = threadIdx.x;
    const int sub  = lane >> 5;
    const int sl   = lane & 31;
    __shared__ float qlds[KDIM];
    __shared__ int   cl[2][64];
    __shared__ unsigned long long pkl[2][64];
    __shared__ int   csh[2];
    __shared__ float ts[2][KNN];
    __shared__ int   ti[2][KNN];

    const float* qrow = q + (size_t)n * (HEADS * KDIM) + h * KDIM;
    #pragma unroll
    for (int j = 0; j < 8; ++j) qlds[j * 64 + lane] = qrow[j * 64 + lane];

    const float* sb = s + (size_t)nh * (2 * NKEYS) + sub * NKEYS;
    unsigned u[16];
    #pragma unroll
    for (int i = 0; i < 16; ++i) u[i] = fmap(sb[i * 32 + sl]);

    unsigned lo = 0, hi = 0xFFFFFFFFu, tau = 0;
    bool found = false;
    for (int iter = 0; iter < 30; ++iter) {
        if (__all(found)) break;
        const unsigned mid = lo + ((hi - lo) >> 1);
        int c = 0;
        #pragma unroll
        for (int i = 0; i < 16; ++i) c += (u[i] >= mid) ? 1 : 0;
        #pragma unroll
        for (int off = 1; off <= 16; off <<= 1) c += __shfl_xor(c, off);
        if (!found) {
            if (c >= 40 && c <= 56) { tau = mid; found = true; }
            else if (c > 56) lo = mid + 1;
            else hi = mid - 1;
        }
    }
    if (!found) tau = lo;

    unsigned msk = 0;
    #pragma unroll
    for (int i = 0; i < 16; ++i) msk |= (u[i] >= tau ? 1u : 0u) << i;
    int mc = __popc(msk);
    int pfx = mc;
    #pragma unroll
    for (int d = 1; d <= 16; d <<= 1) {
        const int t = __shfl_up(pfx, d);
        if (sl >= d) pfx += t;
    }
    int slot = pfx - mc;
    #pragma unroll
    for (int i = 0; i < 16; ++i)
        if ((msk >> i) & 1u) {
            if (slot < 64) cl[sub][slot] = (i << 5) | sl;
            ++slot;
        }
    if (sl == 31) csh[sub] = (pfx < 64) ? pfx : 64;
    __syncthreads();

    #pragma unroll
    for (int p = 0; p < 2; ++p) {
        const int cnt = csh[p];
        const int ci = cl[p][lane < cnt ? lane : cnt - 1];
        const float* kr = keys + ((size_t)(h * 2 + p) * NKEYS + ci) * HALFD;
        const float* qh_ = qlds + p * HALFD;
        float a = 0.f;
        #pragma unroll
        for (int kb = 0; kb < 4; ++kb) {
            float4 rr[16];
            #pragma unroll
            for (int j = 0; j < 16; ++j)
                rr[j] = *(const float4*)(kr + kb * 64 + j * 4);
            #pragma unroll
            for (int j = 0; j < 16; ++j) {
                a = fmaf(qh_[kb * 64 + j * 4 + 0], rr[j].x, a);
                a = fmaf(qh_[kb * 64 + j * 4 + 1], rr[j].y, a);
                a = fmaf(qh_[kb * 64 + j * 4 + 2], rr[j].z, a);
                a = fmaf(qh_[kb * 64 + j * 4 + 3], rr[j].w, a);
            }
        }
        pkl[p][lane] = (lane < cnt)
            ? (((unsigned long long)fmap(a) << 32) | (unsigned)(~ci))
            : ((unsigned long long)fmap(-INFINITY) << 32);
    }
    __syncthreads();

    unsigned long long pk0 = pkl[sub][sl], pk1 = pkl[sub][sl + 32];
    for (int it = 0; it < KNN; ++it) {
        unsigned long long best = pk0 > pk1 ? pk0 : pk1;
        #pragma unroll
        for (int off = 16; off; off >>= 1) {
            const unsigned long long o = shflxor64(best, off);
            if (o > best) best = o;
        }
        if (sl == 0) {
            ts[sub][it] = funmap((unsigned)(best >> 32));
            ti[sub][it] = (int)(~(unsigned)best) & (NKEYS - 1);
        }
        if (pk0 == best) pk0 = 0ull;
        if (pk1 == best) pk1 = 0ull;
    }
    __syncthreads();

    float cv[2]; int cc[2];
    #pragma unroll
    for (int t = 0; t < 2; ++t) {
        const int c = t * 64 + lane;
        int ii = -1, jj = 0, off = 0;
        #pragma unroll
        for (int i = 0; i < 32; ++i) {
            const int cnt = 32 / (i + 1);
            const bool in = (c >= off) && (c < off + cnt);
            ii = in ? i : ii;
            jj = in ? c - off : jj;
            off += cnt;
        }
        if (ii >= 0) { cv[t] = ts[0][ii] + ts[1][jj]; cc[t] = ii * 32 + jj; }
        else         { cv[t] = -INFINITY;             cc[t] = 0x7fffffff;  }
    }

    unsigned used2 = 0;
    float mval = 0.f, myval = -INFINITY;
    int mycombo = 0;
    for (int it = 0; it < KNN; ++it) {
        float bv = -INFINITY; int bc = 0x7fffffff;
        #pragma unroll
        for (int t = 0; t < 2; ++t) {
            const bool live = !((used2 >> t) & 1u);
            const bool better = live &&
                (cv[t] > bv || (cv[t] == bv && cc[t] < bc));
            bv = better ? cv[t] : bv;
            bc = better ? cc[t] : bc;
        }
        float m = bv;
        #pragma unroll
        for (int off = 32; off; off >>= 1) m = fmaxf(m, __shfl_xor(m, off));
        const unsigned long long bal = __ballot(bv == m);
        int combo;
        if (__popcll(bal) == 1) {
            combo = __shfl(bc, (int)(__ffsll(bal) - 1));
        } else {
            unsigned cm = (bv == m) ? (unsigned)bc : 0xffffffffu;
            #pragma unroll
            for (int off = 32; off; off >>= 1) cm = min(cm, __shfl_xor(cm, off));
            combo = (int)cm;
        }
        if (it == 0) mval = m;
        if (lane == it) { myval = m; mycombo = combo; }
        #pragma unroll
        for (int t = 0; t < 2; ++t)
            if (cc[t] == combo) used2 |= 1u << t;
    }

    const float ew = (lane < KNN) ? expf(myval - mval) : 0.f;
    float ssum = ew;
    #pragma unroll
    for (int off = 32; off; off >>= 1) ssum += __shfl_xor(ssum, off);
    if (lane < KNN) {
        const int i1 = ti[0][mycombo >> 5];
        const int i2 = ti[1][mycombo & 31];
        w_out[(size_t)nh * KNN + lane] = ew / ssum;
        idx_out[(size_t)nh * KNN + lane] = i1 * NKEYS + i2;
    }
}

// =================== small-tile f32 NT GEMM: 64x64 (R4-proven) =============
__global__ __launch_bounds__(256)
void gemm_nt(const float* __restrict__ A, int lda,
             const float* __restrict__ B, int ldb,
             float* __restrict__ C, int ldc,
             const float* __restrict__ bias, int K)
{
    __shared__ __align__(16) float as[16][68];
    __shared__ __align__(16) float bs[16][68];
    const int tid = threadIdx.x;
    const int tx = tid & 15, ty = tid >> 4;
    const int m0 = blockIdx.y * 64, n0 = blockIdx.x * 64;
    const int lrow = tid >> 2;
    const int lk4  = (tid & 3) << 2;
    const float* Ap = A + (size_t)(m0 + lrow) * lda + lk4;
    const float* Bp = B + (size_t)(n0 + lrow) * ldb + lk4;
    float acc[4][4] = {};

    float4 av = *(const float4*)(Ap);
    float4 bv = *(const float4*)(Bp);
    for (int k0 = 0; k0 < K; k0 += 16) {
        __syncthreads();
        as[lk4 + 0][lrow] = av.x; as[lk4 + 1][lrow] = av.y;
        as[lk4 + 2][lrow] = av.z; as[lk4 + 3][lrow] = av.w;
        bs[lk4 + 0][lrow] = bv.x; bs[lk4 + 1][lrow] = bv.y;
        bs[lk4 + 2][lrow] = bv.z; bs[lk4 + 3][lrow] = bv.w;
        __syncthreads();
        if (k0 + 16 < K) {
            av = *(const float4*)(Ap + k0 + 16);
            bv = *(const float4*)(Bp + k0 + 16);
        }
        #pragma unroll
        for (int kk = 0; kk < 16; ++kk) {
            const float4 a = *(const float4*)&as[kk][ty << 2];
            const float4 b = *(const float4*)&bs[kk][tx << 2];
            const float ar[4] = {a.x, a.y, a.z, a.w};
            const float br[4] = {b.x, b.y, b.z, b.w};
            #pragma unroll
            for (int i = 0; i < 4; ++i)
                #pragma unroll
                for (int j = 0; j < 4; ++j)
                    acc[i][j] = fmaf(ar[i], br[j], acc[i][j]);
        }
    }

    float4 bb = {0.f, 0.f, 0.f, 0.f};
    if (bias) bb = *(const float4*)(bias + n0 + (tx << 2));
    #pragma unroll
    for (int i = 0; i < 4; ++i) {
        float4 o;
        o.x = acc[i][0] + bb.x; o.y = acc[i][1] + bb.y;
        o.z = acc[i][2] + bb.z; o.w = acc[i][3] + bb.w;
        *(float4*)(C + (size_t)(m0 + (ty << 2) + i) * ldc + n0 + (tx << 2)) = o;
    }
}

// =================== weighted embedding-bag gather + gate ==================
__global__ __launch_bounds__(256)
void gather_kernel(const float* __restrict__ values,
                   const float* __restrict__ w, const int* __restrict__ idx,
                   const float* __restrict__ gate, float* __restrict__ out0)
{
    const int n = blockIdx.x;
    const int t = threadIdx.x;
    __shared__ float sw[HEADS * KNN];
    __shared__ int   sidx[HEADS * KNN];
    if (t < HEADS * KNN) {
        sw[t]   = w[(size_t)n * HEADS * KNN + t];
        sidx[t] = idx[(size_t)n * HEADS * KNN + t];
    }
    __syncthreads();
    const int d0 = t * 2;
    float2 acc = {0.f, 0.f};
    #pragma unroll 8
    for (int k = 0; k < HEADS * KNN; ++k) {
        const float2 v = *(const float2*)(values + (size_t)sidx[k] * DOUT + d0);
        const float ww = sw[k];
        acc.x = fmaf(ww, v.x, acc.x);
        acc.y = fmaf(ww, v.y, acc.y);
    }
    const float2 g = *(const float2*)(gate + (size_t)n * DOUT + d0);
    acc.x *= g.x;
    acc.y *= g.y;
    *(float2*)(out0 + (size_t)n * DOUT + d0) = acc;
}

}  // namespace

extern "C" void kernel_launch(void* const* d_in, const int* in_sizes, int n_in,
                              void* d_out, int out_size, void* d_ws, size_t ws_size,
                              hipStream_t stream)
{
    const float* x      = (const float*)d_in[0];
    const float* Wq     = (const float*)d_in[1];
    const float* bq     = (const float*)d_in[2];
    const float* keys   = (const float*)d_in[3];
    const float* values = (const float*)d_in[4];
    const float* Wsw    = (const float*)d_in[5];
    const float* bsw    = (const float*)d_in[6];
    const float* Wv     = (const float*)d_in[7];
    const float* bv     = (const float*)d_in[8];
    float* out = (float*)d_out;

    // workspace layout
    float*          q    = (float*)d_ws;                                        // 16MB
    unsigned short* qh   = (unsigned short*)(q + (size_t)NROWS * HEADS * KDIM); // 8MB
    float*          s    = (float*)(qh + (size_t)NROWS * HEADS * KDIM);         // 32MB
    unsigned short* xh   = (unsigned short*)(s + (size_t)NROWS * HEADS * 2 * NKEYS);
    unsigned short* xl   = xh + (size_t)NROWS * DIN;
    unsigned short* wh   = xl + (size_t)NROWS * DIN;
    unsigned short* wl   = wh + (size_t)DOUT * DIN;
    unsigned short* kh   = wl + (size_t)DOUT * DIN;
    float*          wsc  = (float*)(kh + (size_t)8 * NKEYS * HALFD);
    int*            idxb = (int*)(wsc + (size_t)NROWS * HEADS * KNN);
    float*          gate = (float*)(idxb + (size_t)NROWS * HEADS * KNN);
    float*          out0 = gate + (size_t)NROWS * DOUT;

    const dim3 blk(256);

    // 1) split x/Wsw -> bf16 hi+lo; keys -> bf16 hi
    split3<<<dim3(1024, 1, 3), blk, 0, stream>>>(
        x, Wsw, keys, xh, xl, wh, wl, kh);

    // 2) q = x @ Wq^T + bq  (exact f32 ascending chain) + bf16-hi dual-store
    gemm_q<<<dim3(16, 16), blk, 0, stream>>>(x, Wq, q, qh, bq);

    // 3) approx scores (z<8, bf16 1-term) + gate (z==8, 3-term split) — LDS MFMA
    mfma_sg<<<dim3(16, 4, 9), blk, 0, stream>>>(
        qh, kh, xh, xl, wh, wl, bsw, s, gate);

    // 4) tau-select -> exact rescore -> exact two-stage top-32 + softmax
    topk2<<<dim3(NROWS * HEADS), dim3(64), 0, stream>>>(
        s, q, keys, wsc, idxb);

    // 5) out0 = (sum_k w*values[idx]) * gate
    gather_kernel<<<dim3(NROWS), blk, 0, stream>>>(values, wsc, idxb, gate, out0);

    // 6) out = out0 @ Wv^T + bv
    gemm_nt<<<dim3(8, 32), blk, 0, stream>>>(
        out0, DOUT, Wv, DOUT, out, DOUT, bv, DOUT);
}

// Round 9
// 343.796 us; speedup vs baseline: 1.3913x; 1.0127x over previous
//
#include <hip/hip_runtime.h>
#include <math.h>

namespace {

constexpr int NROWS = 2048;   // B*T
constexpr int DIN   = 512;
constexpr int DOUT  = 512;
constexpr int HEADS = 4;
constexpr int KDIM  = 512;
constexpr int HALFD = 256;
constexpr int NKEYS = 512;
constexpr int KNN   = 32;

typedef short bf16x8 __attribute__((ext_vector_type(8)));
typedef float f32x4  __attribute__((ext_vector_type(4)));

__device__ inline unsigned short f2bf(float f) {   // round-to-nearest-even
    unsigned u = __float_as_uint(f);
    unsigned r = u + 0x7FFFu + ((u >> 16) & 1u);
    return (unsigned short)(r >> 16);
}
__device__ inline float bf2f(unsigned short h) {
    return __uint_as_float((unsigned)h << 16);
}
__device__ inline unsigned fmap(float f) {
    unsigned u = __float_as_uint(f);
    return (u & 0x80000000u) ? ~u : (u | 0x80000000u);
}
__device__ inline float funmap(unsigned m) {
    unsigned u = (m & 0x80000000u) ? (m & 0x7FFFFFFFu) : ~m;
    return __uint_as_float(u);
}
__device__ inline unsigned long long shflxor64(unsigned long long x, int m) {
    unsigned lo = (unsigned)x, hi = (unsigned)(x >> 32);
    lo = __shfl_xor(lo, m);
    hi = __shfl_xor(hi, m);
    return ((unsigned long long)hi << 32) | lo;
}

// ====== split: x->hi/lo (z0), Wsw->hi/lo (z1), keys->hi (z2), Wv->hi/lo (z3)
__global__ __launch_bounds__(256)
void split4(const float* __restrict__ x, const float* __restrict__ wsw,
            const float* __restrict__ keys, const float* __restrict__ wv,
            unsigned short* __restrict__ xh, unsigned short* __restrict__ xl,
            unsigned short* __restrict__ wh, unsigned short* __restrict__ wl,
            unsigned short* __restrict__ kh,
            unsigned short* __restrict__ vh, unsigned short* __restrict__ vl)
{
    const int z = blockIdx.z;
    const int i = (blockIdx.x * 256 + threadIdx.x) * 4;
    if (z == 2) {                      // keys -> hi only
        if (i >= 1048576) return;
        const float4 v = *(const float4*)(keys + i);
        ushort4 oh;
        oh.x = f2bf(v.x); oh.y = f2bf(v.y); oh.z = f2bf(v.z); oh.w = f2bf(v.w);
        *(ushort4*)(kh + i) = oh;
        return;
    }
    const float* src = (z == 0) ? x : (z == 1) ? wsw : wv;
    unsigned short* ph = (z == 0) ? xh : (z == 1) ? wh : vh;
    unsigned short* pl = (z == 0) ? xl : (z == 1) ? wl : vl;
    const int n = (z == 0) ? 1048576 : 262144;
    if (i >= n) return;
    const float4 v = *(const float4*)(src + i);
    ushort4 oh, ol;
    oh.x = f2bf(v.x); ol.x = f2bf(v.x - bf2f(oh.x));
    oh.y = f2bf(v.y); ol.y = f2bf(v.y - bf2f(oh.y));
    oh.z = f2bf(v.z); ol.z = f2bf(v.z - bf2f(oh.z));
    oh.w = f2bf(v.w); ol.w = f2bf(v.w - bf2f(oh.w));
    *(ushort4*)(ph + i) = oh;
    *(ushort4*)(pl + i) = ol;
}

// =================== q GEMM: 128x64 (R4/R7-proven), exact f32 chain ========
// Dual-stores f32 q and bf16-hi qh.
__global__ __launch_bounds__(256)
void gemm_q(const float* __restrict__ A, const float* __restrict__ B,
            float* __restrict__ C, unsigned short* __restrict__ Ch,
            const float* __restrict__ bias)
{
    constexpr int lda = DIN, ldb = DIN, ldc = HEADS * KDIM, K = DIN;
    const int m0 = blockIdx.y * 128, n0 = blockIdx.x * 64;
    __shared__ __align__(16) float as[16][132];
    __shared__ __align__(16) float bs[16][68];
    const int tid = threadIdx.x;
    const int tx = tid & 15, ty = tid >> 4;
    const int lrA = tid >> 1, lkA = (tid & 1) << 3;
    const int lrB = tid >> 2, lkB = (tid & 3) << 2;
    const float* Ap = A + (size_t)(m0 + lrA) * lda + lkA;
    const float* Bp = B + (size_t)(n0 + lrB) * ldb + lkB;
    float acc[8][4] = {};

    float4 a0 = *(const float4*)(Ap);
    float4 a1 = *(const float4*)(Ap + 4);
    float4 b0 = *(const float4*)(Bp);
    for (int k0 = 0; k0 < K; k0 += 16) {
        __syncthreads();
        as[lkA + 0][lrA] = a0.x; as[lkA + 1][lrA] = a0.y;
        as[lkA + 2][lrA] = a0.z; as[lkA + 3][lrA] = a0.w;
        as[lkA + 4][lrA] = a1.x; as[lkA + 5][lrA] = a1.y;
        as[lkA + 6][lrA] = a1.z; as[lkA + 7][lrA] = a1.w;
        bs[lkB + 0][lrB] = b0.x; bs[lkB + 1][lrB] = b0.y;
        bs[lkB + 2][lrB] = b0.z; bs[lkB + 3][lrB] = b0.w;
        __syncthreads();
        if (k0 + 16 < K) {
            a0 = *(const float4*)(Ap + k0 + 16);
            a1 = *(const float4*)(Ap + k0 + 20);
            b0 = *(const float4*)(Bp + k0 + 16);
        }
        #pragma unroll
        for (int kk = 0; kk < 16; ++kk) {
            const float4 a0v = *(const float4*)&as[kk][ty << 3];
            const float4 a1v = *(const float4*)&as[kk][(ty << 3) + 4];
            const float4 bv  = *(const float4*)&bs[kk][tx << 2];
            const float ar[8] = {a0v.x, a0v.y, a0v.z, a0v.w,
                                 a1v.x, a1v.y, a1v.z, a1v.w};
            const float br[4] = {bv.x, bv.y, bv.z, bv.w};
            #pragma unroll
            for (int i = 0; i < 8; ++i)
                #pragma unroll
                for (int j = 0; j < 4; ++j)
                    acc[i][j] = fmaf(ar[i], br[j], acc[i][j]);
        }
    }

    const float4 bb = *(const float4*)(bias + n0 + (tx << 2));
    #pragma unroll
    for (int i = 0; i < 8; ++i) {
        float4 o;
        o.x = acc[i][0] + bb.x; o.y = acc[i][1] + bb.y;
        o.z = acc[i][2] + bb.z; o.w = acc[i][3] + bb.w;
        const size_t off = (size_t)(m0 + (ty << 3) + i) * ldc + n0 + (tx << 2);
        *(float4*)(C + off) = o;
        ushort4 h;
        h.x = f2bf(o.x); h.y = f2bf(o.y); h.z = f2bf(o.z); h.w = f2bf(o.w);
        *(ushort4*)(Ch + off) = h;
    }
}

// =================== LDS-staged bf16 MFMA: scores (z<8) + gate (z==8) ======
// (R8-proven)  Tile 128x128, BK=64, 4 waves (2x2), 16x16x32 MFMA, T2 swizzle.
__global__ __launch_bounds__(256)
void mfma_sg(const unsigned short* __restrict__ qh,
             const unsigned short* __restrict__ kh,
             const unsigned short* __restrict__ xh, const unsigned short* __restrict__ xl,
             const unsigned short* __restrict__ wh, const unsigned short* __restrict__ wl,
             const float* __restrict__ bsw,
             float* __restrict__ s, float* __restrict__ gate)
{
    __shared__ __align__(16) unsigned short Al[128 * 64];
    __shared__ __align__(16) unsigned short Bl[128 * 64];
    const int tid  = threadIdx.x;
    const int wid  = tid >> 6, lane = tid & 63;
    const int r16  = lane & 15, kc = lane >> 4;
    const int wr   = wid >> 1, wc = wid & 1;
    const int z    = blockIdx.z;
    const int bx   = blockIdx.x, by = blockIdx.y;
    const int srow = tid >> 1;
    const int skb  = (tid & 1) << 5;
    const unsigned swzw = (unsigned)((srow & 7) << 4);

    f32x4 acc[4][4] = {};
    const int nterm = (z < 8) ? 1 : 3;

    for (int term = 0; term < nterm; ++term) {
        const unsigned short *Ag, *Bg;
        int K;
        if (z < 8) {
            Ag = qh + (size_t)(bx * 128 + srow) * (HEADS * KDIM)
               + (z >> 1) * KDIM + (z & 1) * HALFD + skb;
            Bg = kh + ((size_t)z * NKEYS + by * 128 + srow) * HALFD + skb;
            K = HALFD;
        } else {
            Ag = ((term == 2) ? xl : xh) + (size_t)(bx * 128 + srow) * DIN + skb;
            Bg = ((term == 1) ? wl : wh) + (size_t)(by * 128 + srow) * DIN + skb;
            K = DIN;
        }
        for (int k0 = 0; k0 < K; k0 += 64) {
            __syncthreads();
            #pragma unroll
            for (int j = 0; j < 4; ++j) {
                const uint4 va = *(const uint4*)(Ag + k0 + j * 8);
                const uint4 vb = *(const uint4*)(Bg + k0 + j * 8);
                const unsigned boff = (unsigned)(srow * 128 + (skb + j * 8) * 2) ^ swzw;
                *(uint4*)((char*)Al + boff) = va;
                *(uint4*)((char*)Bl + boff) = vb;
            }
            __syncthreads();
            #pragma unroll
            for (int ks = 0; ks < 2; ++ks) {
                bf16x8 af[4], bf[4];
                #pragma unroll
                for (int f = 0; f < 4; ++f) {
                    const int am = wr * 64 + f * 16 + r16;
                    af[f] = *(const bf16x8*)((const char*)Al +
                        ((unsigned)(am * 128 + ks * 64 + kc * 16) ^ ((am & 7) << 4)));
                    const int bn = wc * 64 + f * 16 + r16;
                    bf[f] = *(const bf16x8*)((const char*)Bl +
                        ((unsigned)(bn * 128 + ks * 64 + kc * 16) ^ ((bn & 7) << 4)));
                }
                #pragma unroll
                for (int fm = 0; fm < 4; ++fm)
                    #pragma unroll
                    for (int fn = 0; fn < 4; ++fn)
                        acc[fm][fn] = __builtin_amdgcn_mfma_f32_16x16x32_bf16(
                            af[fm], bf[fn], acc[fm][fn], 0, 0, 0);
            }
        }
    }

    #pragma unroll
    for (int fm = 0; fm < 4; ++fm) {
        const int row = bx * 128 + wr * 64 + fm * 16 + kc * 4;
        #pragma unroll
        for (int fn = 0; fn < 4; ++fn) {
            const int col = by * 128 + wc * 64 + fn * 16 + r16;
            #pragma unroll
            for (int r = 0; r < 4; ++r) {
                float v = acc[fm][fn][r];
                if (z < 8) {
                    s[(size_t)(row + r) * (HEADS * 2 * NKEYS) + z * NKEYS + col] = v;
                } else {
                    v += bsw[col];
                    v = v / (1.f + expf(-v));
                    gate[(size_t)(row + r) * DOUT + col] = v;
                }
            }
        }
    }
}

// =================== topk v2 (R7-proven): tau-select -> exact rescore ======
__global__ __launch_bounds__(64)
void topk2(const float* __restrict__ s, const float* __restrict__ q,
           const float* __restrict__ keys,
           float* __restrict__ w_out, int* __restrict__ idx_out)
{
    const int nh   = blockIdx.x;
    const int n    = nh >> 2;
    const int h    = nh & 3;
    const int lane = threadIdx.x;
    const int sub  = lane >> 5;
    const int sl   = lane & 31;
    __shared__ float qlds[KDIM];
    __shared__ int   cl[2][64];
    __shared__ unsigned long long pkl[2][64];
    __shared__ int   csh[2];
    __shared__ float ts[2][KNN];
    __shared__ int   ti[2][KNN];

    const float* qrow = q + (size_t)n * (HEADS * KDIM) + h * KDIM;
    #pragma unroll
    for (int j = 0; j < 8; ++j) qlds[j * 64 + lane] = qrow[j * 64 + lane];

    const float* sb = s + (size_t)nh * (2 * NKEYS) + sub * NKEYS;
    unsigned u[16];
    #pragma unroll
    for (int i = 0; i < 16; ++i) u[i] = fmap(sb[i * 32 + sl]);

    unsigned lo = 0, hi = 0xFFFFFFFFu, tau = 0;
    bool found = false;
    for (int iter = 0; iter < 30; ++iter) {
        if (__all(found)) break;
        const unsigned mid = lo + ((hi - lo) >> 1);
        int c = 0;
        #pragma unroll
        for (int i = 0; i < 16; ++i) c += (u[i] >= mid) ? 1 : 0;
        #pragma unroll
        for (int off = 1; off <= 16; off <<= 1) c += __shfl_xor(c, off);
        if (!found) {
            if (c >= 40 && c <= 56) { tau = mid; found = true; }
            else if (c > 56) lo = mid + 1;
            else hi = mid - 1;
        }
    }
    if (!found) tau = lo;

    unsigned msk = 0;
    #pragma unroll
    for (int i = 0; i < 16; ++i) msk |= (u[i] >= tau ? 1u : 0u) << i;
    int mc = __popc(msk);
    int pfx = mc;
    #pragma unroll
    for (int d = 1; d <= 16; d <<= 1) {
        const int t = __shfl_up(pfx, d);
        if (sl >= d) pfx += t;
    }
    int slot = pfx - mc;
    #pragma unroll
    for (int i = 0; i < 16; ++i)
        if ((msk >> i) & 1u) {
            if (slot < 64) cl[sub][slot] = (i << 5) | sl;
            ++slot;
        }
    if (sl == 31) csh[sub] = (pfx < 64) ? pfx : 64;
    __syncthreads();

    #pragma unroll
    for (int p = 0; p < 2; ++p) {
        const int cnt = csh[p];
        const int ci = cl[p][lane < cnt ? lane : cnt - 1];
        const float* kr = keys + ((size_t)(h * 2 + p) * NKEYS + ci) * HALFD;
        const float* qh_ = qlds + p * HALFD;
        float a = 0.f;
        #pragma unroll
        for (int kb = 0; kb < 4; ++kb) {
            float4 rr[16];
            #pragma unroll
            for (int j = 0; j < 16; ++j)
                rr[j] = *(const float4*)(kr + kb * 64 + j * 4);
            #pragma unroll
            for (int j = 0; j < 16; ++j) {
                a = fmaf(qh_[kb * 64 + j * 4 + 0], rr[j].x, a);
                a = fmaf(qh_[kb * 64 + j * 4 + 1], rr[j].y, a);
                a = fmaf(qh_[kb * 64 + j * 4 + 2], rr[j].z, a);
                a = fmaf(qh_[kb * 64 + j * 4 + 3], rr[j].w, a);
            }
        }
        pkl[p][lane] = (lane < cnt)
            ? (((unsigned long long)fmap(a) << 32) | (unsigned)(~ci))
            : ((unsigned long long)fmap(-INFINITY) << 32);
    }
    __syncthreads();

    unsigned long long pk0 = pkl[sub][sl], pk1 = pkl[sub][sl + 32];
    for (int it = 0; it < KNN; ++it) {
        unsigned long long best = pk0 > pk1 ? pk0 : pk1;
        #pragma unroll
        for (int off = 16; off; off >>= 1) {
            const unsigned long long o = shflxor64(best, off);
            if (o > best) best = o;
        }
        if (sl == 0) {
            ts[sub][it] = funmap((unsigned)(best >> 32));
            ti[sub][it] = (int)(~(unsigned)best) & (NKEYS - 1);
        }
        if (pk0 == best) pk0 = 0ull;
        if (pk1 == best) pk1 = 0ull;
    }
    __syncthreads();

    float cv[2]; int cc[2];
    #pragma unroll
    for (int t = 0; t < 2; ++t) {
        const int c = t * 64 + lane;
        int ii = -1, jj = 0, off = 0;
        #pragma unroll
        for (int i = 0; i < 32; ++i) {
            const int cnt = 32 / (i + 1);
            const bool in = (c >= off) && (c < off + cnt);
            ii = in ? i : ii;
            jj = in ? c - off : jj;
            off += cnt;
        }
        if (ii >= 0) { cv[t] = ts[0][ii] + ts[1][jj]; cc[t] = ii * 32 + jj; }
        else         { cv[t] = -INFINITY;             cc[t] = 0x7fffffff;  }
    }

    unsigned used2 = 0;
    float mval = 0.f, myval = -INFINITY;
    int mycombo = 0;
    for (int it = 0; it < KNN; ++it) {
        float bv = -INFINITY; int bc = 0x7fffffff;
        #pragma unroll
        for (int t = 0; t < 2; ++t) {
            const bool live = !((used2 >> t) & 1u);
            const bool better = live &&
                (cv[t] > bv || (cv[t] == bv && cc[t] < bc));
            bv = better ? cv[t] : bv;
            bc = better ? cc[t] : bc;
        }
        float m = bv;
        #pragma unroll
        for (int off = 32; off; off >>= 1) m = fmaxf(m, __shfl_xor(m, off));
        const unsigned long long bal = __ballot(bv == m);
        int combo;
        if (__popcll(bal) == 1) {
            combo = __shfl(bc, (int)(__ffsll(bal) - 1));
        } else {
            unsigned cm = (bv == m) ? (unsigned)bc : 0xffffffffu;
            #pragma unroll
            for (int off = 32; off; off >>= 1) cm = min(cm, __shfl_xor(cm, off));
            combo = (int)cm;
        }
        if (it == 0) mval = m;
        if (lane == it) { myval = m; mycombo = combo; }
        #pragma unroll
        for (int t = 0; t < 2; ++t)
            if (cc[t] == combo) used2 |= 1u << t;
    }

    const float ew = (lane < KNN) ? expf(myval - mval) : 0.f;
    float ssum = ew;
    #pragma unroll
    for (int off = 32; off; off >>= 1) ssum += __shfl_xor(ssum, off);
    if (lane < KNN) {
        const int i1 = ti[0][mycombo >> 5];
        const int i2 = ti[1][mycombo & 31];
        w_out[(size_t)nh * KNN + lane] = ew / ssum;
        idx_out[(size_t)nh * KNN + lane] = i1 * NKEYS + i2;
    }
}

// =========== weighted embedding-bag gather + gate -> bf16 hi/lo out0 =======
__global__ __launch_bounds__(256)
void gather_kernel(const float* __restrict__ values,
                   const float* __restrict__ w, const int* __restrict__ idx,
                   const float* __restrict__ gate,
                   unsigned short* __restrict__ o0h, unsigned short* __restrict__ o0l)
{
    const int n = blockIdx.x;
    const int t = threadIdx.x;
    __shared__ float sw[HEADS * KNN];
    __shared__ int   sidx[HEADS * KNN];
    if (t < HEADS * KNN) {
        sw[t]   = w[(size_t)n * HEADS * KNN + t];
        sidx[t] = idx[(size_t)n * HEADS * KNN + t];
    }
    __syncthreads();
    const int d0 = t * 2;
    float2 acc = {0.f, 0.f};
    #pragma unroll 8
    for (int k = 0; k < HEADS * KNN; ++k) {
        const float2 v = *(const float2*)(values + (size_t)sidx[k] * DOUT + d0);
        const float ww = sw[k];
        acc.x = fmaf(ww, v.x, acc.x);
        acc.y = fmaf(ww, v.y, acc.y);
    }
    const float2 g = *(const float2*)(gate + (size_t)n * DOUT + d0);
    const float vx = acc.x * g.x;
    const float vy = acc.y * g.y;
    ushort2 h, l;
    h.x = f2bf(vx); l.x = f2bf(vx - bf2f(h.x));
    h.y = f2bf(vy); l.y = f2bf(vy - bf2f(h.y));
    *(ushort2*)(o0h + (size_t)n * DOUT + d0) = h;
    *(ushort2*)(o0l + (size_t)n * DOUT + d0) = l;
}

// =========== final projection: out = out0 @ Wv^T + bv (3-term MFMA) ========
// Tile 64x64, 4 waves (2x2, each 32x32), BK=64, T2 swizzle.
__global__ __launch_bounds__(256)
void mfma_out(const unsigned short* __restrict__ o0h, const unsigned short* __restrict__ o0l,
              const unsigned short* __restrict__ vh, const unsigned short* __restrict__ vl,
              const float* __restrict__ bv, float* __restrict__ out)
{
    __shared__ __align__(16) unsigned short Al[64 * 64];
    __shared__ __align__(16) unsigned short Bl[64 * 64];
    const int tid = threadIdx.x;
    const int wid = tid >> 6, lane = tid & 63;
    const int r16 = lane & 15, kc = lane >> 4;
    const int wr = wid >> 1, wc = wid & 1;
    const int m0 = blockIdx.x * 64, n0 = blockIdx.y * 64;
    const int srow = tid >> 2;           // 0..63
    const int skb  = (tid & 3) << 4;     // k-base in bf16: 0,16,32,48
    const unsigned swzw = (unsigned)((srow & 7) << 4);

    f32x4 acc[2][2] = {};
    #pragma unroll
    for (int term = 0; term < 3; ++term) {
        const unsigned short* Ag = ((term == 2) ? o0l : o0h) + (size_t)(m0 + srow) * DOUT + skb;
        const unsigned short* Bg = ((term == 1) ? vl : vh) + (size_t)(n0 + srow) * DOUT + skb;
        for (int k0 = 0; k0 < DOUT; k0 += 64) {
            __syncthreads();
            const uint4 va0 = *(const uint4*)(Ag + k0);
            const uint4 va1 = *(const uint4*)(Ag + k0 + 8);
            const uint4 vb0 = *(const uint4*)(Bg + k0);
            const uint4 vb1 = *(const uint4*)(Bg + k0 + 8);
            const unsigned b0 = (unsigned)(srow * 128 + skb * 2) ^ swzw;
            const unsigned b1 = (unsigned)(srow * 128 + skb * 2 + 16) ^ swzw;
            *(uint4*)((char*)Al + b0) = va0; *(uint4*)((char*)Al + b1) = va1;
            *(uint4*)((char*)Bl + b0) = vb0; *(uint4*)((char*)Bl + b1) = vb1;
            __syncthreads();
            #pragma unroll
            for (int ks = 0; ks < 2; ++ks) {
                bf16x8 af[2], bf[2];
                #pragma unroll
                for (int f = 0; f < 2; ++f) {
                    const int am = wr * 32 + f * 16 + r16;
                    af[f] = *(const bf16x8*)((const char*)Al +
                        ((unsigned)(am * 128 + ks * 64 + kc * 16) ^ ((am & 7) << 4)));
                    const int bn = wc * 32 + f * 16 + r16;
                    bf[f] = *(const bf16x8*)((const char*)Bl +
                        ((unsigned)(bn * 128 + ks * 64 + kc * 16) ^ ((bn & 7) << 4)));
                }
                #pragma unroll
                for (int fm = 0; fm < 2; ++fm)
                    #pragma unroll
                    for (int fn = 0; fn < 2; ++fn)
                        acc[fm][fn] = __builtin_amdgcn_mfma_f32_16x16x32_bf16(
                            af[fm], bf[fn], acc[fm][fn], 0, 0, 0);
            }
        }
    }

    #pragma unroll
    for (int fm = 0; fm < 2; ++fm) {
        const int row = m0 + wr * 32 + fm * 16 + kc * 4;
        #pragma unroll
        for (int fn = 0; fn < 2; ++fn) {
            const int col = n0 + wc * 32 + fn * 16 + r16;
            const float b = bv[col];
            #pragma unroll
            for (int r = 0; r < 4; ++r)
                out[(size_t)(row + r) * DOUT + col] = acc[fm][fn][r] + b;
        }
    }
}

}  // namespace

extern "C" void kernel_launch(void* const* d_in, const int* in_sizes, int n_in,
                              void* d_out, int out_size, void* d_ws, size_t ws_size,
                              hipStream_t stream)
{
    const float* x      = (const float*)d_in[0];
    const float* Wq     = (const float*)d_in[1];
    const float* bq     = (const float*)d_in[2];
    const float* keys   = (const float*)d_in[3];
    const float* values = (const float*)d_in[4];
    const float* Wsw    = (const float*)d_in[5];
    const float* bsw    = (const float*)d_in[6];
    const float* Wv     = (const float*)d_in[7];
    const float* bv     = (const float*)d_in[8];
    float* out = (float*)d_out;

    // workspace layout
    float*          q    = (float*)d_ws;                                        // 16MB
    unsigned short* qh   = (unsigned short*)(q + (size_t)NROWS * HEADS * KDIM); // 8MB
    float*          s    = (float*)(qh + (size_t)NROWS * HEADS * KDIM);         // 32MB
    unsigned short* xh   = (unsigned short*)(s + (size_t)NROWS * HEADS * 2 * NKEYS);
    unsigned short* xl   = xh + (size_t)NROWS * DIN;
    unsigned short* wh   = xl + (size_t)NROWS * DIN;
    unsigned short* wl   = wh + (size_t)DOUT * DIN;
    unsigned short* kh   = wl + (size_t)DOUT * DIN;
    unsigned short* vh   = kh + (size_t)8 * NKEYS * HALFD;
    unsigned short* vl   = vh + (size_t)DOUT * DOUT;
    float*          wsc  = (float*)(vl + (size_t)DOUT * DOUT);
    int*            idxb = (int*)(wsc + (size_t)NROWS * HEADS * KNN);
    float*          gate = (float*)(idxb + (size_t)NROWS * HEADS * KNN);
    unsigned short* o0h  = (unsigned short*)(gate + (size_t)NROWS * DOUT);
    unsigned short* o0l  = o0h + (size_t)NROWS * DOUT;

    const dim3 blk(256);

    // 1) split x/Wsw/Wv -> bf16 hi+lo; keys -> bf16 hi
    split4<<<dim3(1024, 1, 4), blk, 0, stream>>>(
        x, Wsw, keys, Wv, xh, xl, wh, wl, kh, vh, vl);

    // 2) q = x @ Wq^T + bq  (exact f32 ascending chain, 512 blocks) + bf16-hi
    gemm_q<<<dim3(32, 16), blk, 0, stream>>>(x, Wq, q, qh, bq);

    // 3) approx scores (z<8, bf16 1-term) + gate (z==8, 3-term) — LDS MFMA
    mfma_sg<<<dim3(16, 4, 9), blk, 0, stream>>>(
        qh, kh, xh, xl, wh, wl, bsw, s, gate);

    // 4) tau-select -> exact rescore -> exact two-stage top-32 + softmax
    topk2<<<dim3(NROWS * HEADS), dim3(64), 0, stream>>>(
        s, q, keys, wsc, idxb);

    // 5) out0 = (sum_k w*values[idx]) * gate  -> bf16 hi/lo
    gather_kernel<<<dim3(NROWS), blk, 0, stream>>>(
        values, wsc, idxb, gate, o0h, o0l);

    // 6) out = out0 @ Wv^T + bv  (3-term split MFMA)
    mfma_out<<<dim3(32, 8), blk, 0, stream>>>(o0h, o0l, vh, vl, bv, out);
}

// Round 10
// 339.284 us; speedup vs baseline: 1.4098x; 1.0133x over previous
//
#include <hip/hip_runtime.h>
#include <math.h>

namespace {

constexpr int NROWS = 2048;   // B*T
constexpr int DIN   = 512;
constexpr int DOUT  = 512;
constexpr int HEADS = 4;
constexpr int KDIM  = 512;
constexpr int HALFD = 256;
constexpr int NKEYS = 512;
constexpr int KNN   = 32;

typedef short bf16x8 __attribute__((ext_vector_type(8)));
typedef float f32x4  __attribute__((ext_vector_type(4)));

__device__ inline unsigned short f2bf(float f) {   // round-to-nearest-even
    unsigned u = __float_as_uint(f);
    unsigned r = u + 0x7FFFu + ((u >> 16) & 1u);
    return (unsigned short)(r >> 16);
}
__device__ inline float bf2f(unsigned short h) {
    return __uint_as_float((unsigned)h << 16);
}
__device__ inline unsigned fmap(float f) {
    unsigned u = __float_as_uint(f);
    return (u & 0x80000000u) ? ~u : (u | 0x80000000u);
}
__device__ inline float funmap(unsigned m) {
    unsigned u = (m & 0x80000000u) ? (m & 0x7FFFFFFFu) : ~m;
    return __uint_as_float(u);
}
__device__ inline unsigned long long shflxor64(unsigned long long x, int m) {
    unsigned lo = (unsigned)x, hi = (unsigned)(x >> 32);
    lo = __shfl_xor(lo, m);
    hi = __shfl_xor(hi, m);
    return ((unsigned long long)hi << 32) | lo;
}
// full 64-lane bitonic sort, descending by u64 key; lane l ends with rank-l
__device__ inline unsigned long long bitonic64_desc(unsigned long long v, int lane) {
    #pragma unroll
    for (int k = 2; k <= 64; k <<= 1) {
        #pragma unroll
        for (int j = k >> 1; j > 0; j >>= 1) {
            const unsigned long long o = shflxor64(v, j);
            const bool keepMax = (((lane & j) == 0) == ((lane & k) == 0));
            const bool oGreater = o > v;
            v = (keepMax == oGreater) ? o : v;
        }
    }
    return v;
}

// ====== split: x->hi/lo (z0), Wsw->hi/lo (z1), keys->hi (z2), Wv->hi/lo (z3)
__global__ __launch_bounds__(256)
void split4(const float* __restrict__ x, const float* __restrict__ wsw,
            const float* __restrict__ keys, const float* __restrict__ wv,
            unsigned short* __restrict__ xh, unsigned short* __restrict__ xl,
            unsigned short* __restrict__ wh, unsigned short* __restrict__ wl,
            unsigned short* __restrict__ kh,
            unsigned short* __restrict__ vh, unsigned short* __restrict__ vl)
{
    const int z = blockIdx.z;
    const int i = (blockIdx.x * 256 + threadIdx.x) * 4;
    if (z == 2) {                      // keys -> hi only
        if (i >= 1048576) return;
        const float4 v = *(const float4*)(keys + i);
        ushort4 oh;
        oh.x = f2bf(v.x); oh.y = f2bf(v.y); oh.z = f2bf(v.z); oh.w = f2bf(v.w);
        *(ushort4*)(kh + i) = oh;
        return;
    }
    const float* src = (z == 0) ? x : (z == 1) ? wsw : wv;
    unsigned short* ph = (z == 0) ? xh : (z == 1) ? wh : vh;
    unsigned short* pl = (z == 0) ? xl : (z == 1) ? wl : vl;
    const int n = (z == 0) ? 1048576 : 262144;
    if (i >= n) return;
    const float4 v = *(const float4*)(src + i);
    ushort4 oh, ol;
    oh.x = f2bf(v.x); ol.x = f2bf(v.x - bf2f(oh.x));
    oh.y = f2bf(v.y); ol.y = f2bf(v.y - bf2f(oh.y));
    oh.z = f2bf(v.z); ol.z = f2bf(v.z - bf2f(oh.z));
    oh.w = f2bf(v.w); ol.w = f2bf(v.w - bf2f(oh.w));
    *(ushort4*)(ph + i) = oh;
    *(ushort4*)(pl + i) = ol;
}

// =================== q GEMM: 64x64 tile, 4x4 micro, grid 1024 ==============
// Per-output chain: k-ascending serial fmaf (bitwise == R4/R9 q).
// Dual-stores f32 q and bf16-hi qh.  1024 blocks -> 4/CU -> 4 waves/SIMD.
__global__ __launch_bounds__(256)
void gemm_q(const float* __restrict__ A, const float* __restrict__ B,
            float* __restrict__ C, unsigned short* __restrict__ Ch,
            const float* __restrict__ bias)
{
    constexpr int ldc = HEADS * KDIM, K = DIN;
    __shared__ __align__(16) float as[16][68];
    __shared__ __align__(16) float bs[16][68];
    const int tid = threadIdx.x;
    const int tx = tid & 15, ty = tid >> 4;
    const int m0 = blockIdx.y * 64, n0 = blockIdx.x * 64;
    const int lrow = tid >> 2;
    const int lk4  = (tid & 3) << 2;
    const float* Ap = A + (size_t)(m0 + lrow) * DIN + lk4;
    const float* Bp = B + (size_t)(n0 + lrow) * DIN + lk4;
    float acc[4][4] = {};

    float4 av = *(const float4*)(Ap);
    float4 bv = *(const float4*)(Bp);
    for (int k0 = 0; k0 < K; k0 += 16) {
        __syncthreads();
        as[lk4 + 0][lrow] = av.x; as[lk4 + 1][lrow] = av.y;
        as[lk4 + 2][lrow] = av.z; as[lk4 + 3][lrow] = av.w;
        bs[lk4 + 0][lrow] = bv.x; bs[lk4 + 1][lrow] = bv.y;
        bs[lk4 + 2][lrow] = bv.z; bs[lk4 + 3][lrow] = bv.w;
        __syncthreads();
        if (k0 + 16 < K) {
            av = *(const float4*)(Ap + k0 + 16);
            bv = *(const float4*)(Bp + k0 + 16);
        }
        #pragma unroll
        for (int kk = 0; kk < 16; ++kk) {
            const float4 a = *(const float4*)&as[kk][ty << 2];
            const float4 b = *(const float4*)&bs[kk][tx << 2];
            const float ar[4] = {a.x, a.y, a.z, a.w};
            const float br[4] = {b.x, b.y, b.z, b.w};
            #pragma unroll
            for (int i = 0; i < 4; ++i)
                #pragma unroll
                for (int j = 0; j < 4; ++j)
                    acc[i][j] = fmaf(ar[i], br[j], acc[i][j]);
        }
    }

    const float4 bb = *(const float4*)(bias + n0 + (tx << 2));
    #pragma unroll
    for (int i = 0; i < 4; ++i) {
        float4 o;
        o.x = acc[i][0] + bb.x; o.y = acc[i][1] + bb.y;
        o.z = acc[i][2] + bb.z; o.w = acc[i][3] + bb.w;
        const size_t off = (size_t)(m0 + (ty << 2) + i) * ldc + n0 + (tx << 2);
        *(float4*)(C + off) = o;
        ushort4 h;
        h.x = f2bf(o.x); h.y = f2bf(o.y); h.z = f2bf(o.z); h.w = f2bf(o.w);
        *(ushort4*)(Ch + off) = h;
    }
}

// =================== LDS-staged bf16 MFMA: scores (z<8) + gate (z==8) ======
// (R8-proven)  Tile 128x128, BK=64, 4 waves (2x2), 16x16x32 MFMA, T2 swizzle.
__global__ __launch_bounds__(256)
void mfma_sg(const unsigned short* __restrict__ qh,
             const unsigned short* __restrict__ kh,
             const unsigned short* __restrict__ xh, const unsigned short* __restrict__ xl,
             const unsigned short* __restrict__ wh, const unsigned short* __restrict__ wl,
             const float* __restrict__ bsw,
             float* __restrict__ s, float* __restrict__ gate)
{
    __shared__ __align__(16) unsigned short Al[128 * 64];
    __shared__ __align__(16) unsigned short Bl[128 * 64];
    const int tid  = threadIdx.x;
    const int wid  = tid >> 6, lane = tid & 63;
    const int r16  = lane & 15, kc = lane >> 4;
    const int wr   = wid >> 1, wc = wid & 1;
    const int z    = blockIdx.z;
    const int bx   = blockIdx.x, by = blockIdx.y;
    const int srow = tid >> 1;
    const int skb  = (tid & 1) << 5;
    const unsigned swzw = (unsigned)((srow & 7) << 4);

    f32x4 acc[4][4] = {};
    const int nterm = (z < 8) ? 1 : 3;

    for (int term = 0; term < nterm; ++term) {
        const unsigned short *Ag, *Bg;
        int K;
        if (z < 8) {
            Ag = qh + (size_t)(bx * 128 + srow) * (HEADS * KDIM)
               + (z >> 1) * KDIM + (z & 1) * HALFD + skb;
            Bg = kh + ((size_t)z * NKEYS + by * 128 + srow) * HALFD + skb;
            K = HALFD;
        } else {
            Ag = ((term == 2) ? xl : xh) + (size_t)(bx * 128 + srow) * DIN + skb;
            Bg = ((term == 1) ? wl : wh) + (size_t)(by * 128 + srow) * DIN + skb;
            K = DIN;
        }
        for (int k0 = 0; k0 < K; k0 += 64) {
            __syncthreads();
            #pragma unroll
            for (int j = 0; j < 4; ++j) {
                const uint4 va = *(const uint4*)(Ag + k0 + j * 8);
                const uint4 vb = *(const uint4*)(Bg + k0 + j * 8);
                const unsigned boff = (unsigned)(srow * 128 + (skb + j * 8) * 2) ^ swzw;
                *(uint4*)((char*)Al + boff) = va;
                *(uint4*)((char*)Bl + boff) = vb;
            }
            __syncthreads();
            #pragma unroll
            for (int ks = 0; ks < 2; ++ks) {
                bf16x8 af[4], bf[4];
                #pragma unroll
                for (int f = 0; f < 4; ++f) {
                    const int am = wr * 64 + f * 16 + r16;
                    af[f] = *(const bf16x8*)((const char*)Al +
                        ((unsigned)(am * 128 + ks * 64 + kc * 16) ^ ((am & 7) << 4)));
                    const int bn = wc * 64 + f * 16 + r16;
                    bf[f] = *(const bf16x8*)((const char*)Bl +
                        ((unsigned)(bn * 128 + ks * 64 + kc * 16) ^ ((bn & 7) << 4)));
                }
                #pragma unroll
                for (int fm = 0; fm < 4; ++fm)
                    #pragma unroll
                    for (int fn = 0; fn < 4; ++fn)
                        acc[fm][fn] = __builtin_amdgcn_mfma_f32_16x16x32_bf16(
                            af[fm], bf[fn], acc[fm][fn], 0, 0, 0);
            }
        }
    }

    #pragma unroll
    for (int fm = 0; fm < 4; ++fm) {
        const int row = bx * 128 + wr * 64 + fm * 16 + kc * 4;
        #pragma unroll
        for (int fn = 0; fn < 4; ++fn) {
            const int col = by * 128 + wc * 64 + fn * 16 + r16;
            #pragma unroll
            for (int r = 0; r < 4; ++r) {
                float v = acc[fm][fn][r];
                if (z < 8) {
                    s[(size_t)(row + r) * (HEADS * 2 * NKEYS) + z * NKEYS + col] = v;
                } else {
                    v += bsw[col];
                    v = v / (1.f + expf(-v));
                    gate[(size_t)(row + r) * DOUT + col] = v;
                }
            }
        }
    }
}

// ====== topk v3: tau-select -> exact rescore -> bitonic top-32 -> stage 2 ==
__global__ __launch_bounds__(64)
void topk3(const float* __restrict__ s, const float* __restrict__ q,
           const float* __restrict__ keys,
           float* __restrict__ w_out, int* __restrict__ idx_out)
{
    const int nh   = blockIdx.x;
    const int n    = nh >> 2;
    const int h    = nh & 3;
    const int lane = threadIdx.x;
    const int sub  = lane >> 5;
    const int sl   = lane & 31;
    __shared__ float qlds[KDIM];
    __shared__ int   cl[2][64];
    __shared__ unsigned long long pkl[2][64];
    __shared__ int   csh[2];
    __shared__ float ts[2][KNN];
    __shared__ int   ti[2][KNN];

    const float* qrow = q + (size_t)n * (HEADS * KDIM) + h * KDIM;
    #pragma unroll
    for (int j = 0; j < 8; ++j) qlds[j * 64 + lane] = qrow[j * 64 + lane];

    const float* sb = s + (size_t)nh * (2 * NKEYS) + sub * NKEYS;
    unsigned u[16];
    #pragma unroll
    for (int i = 0; i < 16; ++i) u[i] = fmap(sb[i * 32 + sl]);

    unsigned lo = 0, hi = 0xFFFFFFFFu, tau = 0;
    bool found = false;
    for (int iter = 0; iter < 30; ++iter) {
        if (__all(found)) break;
        const unsigned mid = lo + ((hi - lo) >> 1);
        int c = 0;
        #pragma unroll
        for (int i = 0; i < 16; ++i) c += (u[i] >= mid) ? 1 : 0;
        #pragma unroll
        for (int off = 1; off <= 16; off <<= 1) c += __shfl_xor(c, off);
        if (!found) {
            if (c >= 40 && c <= 56) { tau = mid; found = true; }
            else if (c > 56) lo = mid + 1;
            else hi = mid - 1;
        }
    }
    if (!found) tau = lo;

    unsigned msk = 0;
    #pragma unroll
    for (int i = 0; i < 16; ++i) msk |= (u[i] >= tau ? 1u : 0u) << i;
    int mc = __popc(msk);
    int pfx = mc;
    #pragma unroll
    for (int d = 1; d <= 16; d <<= 1) {
        const int t = __shfl_up(pfx, d);
        if (sl >= d) pfx += t;
    }
    int slot = pfx - mc;
    #pragma unroll
    for (int i = 0; i < 16; ++i)
        if ((msk >> i) & 1u) {
            if (slot < 64) cl[sub][slot] = (i << 5) | sl;
            ++slot;
        }
    if (sl == 31) csh[sub] = (pfx < 64) ? pfx : 64;
    __syncthreads();

    // exact rescore (ascending-k fmaf chain, bitwise == R2 score GEMM)
    #pragma unroll
    for (int p = 0; p < 2; ++p) {
        const int cnt = csh[p];
        const int ci = cl[p][lane < cnt ? lane : cnt - 1];
        const float* kr = keys + ((size_t)(h * 2 + p) * NKEYS + ci) * HALFD;
        const float* qh_ = qlds + p * HALFD;
        float a = 0.f;
        #pragma unroll
        for (int kb = 0; kb < 4; ++kb) {
            float4 rr[16];
            #pragma unroll
            for (int j = 0; j < 16; ++j)
                rr[j] = *(const float4*)(kr + kb * 64 + j * 4);
            #pragma unroll
            for (int j = 0; j < 16; ++j) {
                a = fmaf(qh_[kb * 64 + j * 4 + 0], rr[j].x, a);
                a = fmaf(qh_[kb * 64 + j * 4 + 1], rr[j].y, a);
                a = fmaf(qh_[kb * 64 + j * 4 + 2], rr[j].z, a);
                a = fmaf(qh_[kb * 64 + j * 4 + 3], rr[j].w, a);
            }
        }
        pkl[p][lane] = (lane < cnt)
            ? (((unsigned long long)fmap(a) << 32) | (unsigned)(~ci))
            : ((unsigned long long)fmap(-INFINITY) << 32);
    }
    __syncthreads();

    // stage C: bitonic-64 descending sort per half; lane<32 holds top-32
    #pragma unroll
    for (int p = 0; p < 2; ++p) {
        unsigned long long v = bitonic64_desc(pkl[p][lane], lane);
        if (lane < KNN) {
            ts[p][lane] = funmap((unsigned)(v >> 32));
            ti[p][lane] = (int)(~(unsigned)v) & (NKEYS - 1);
        }
    }
    __syncthreads();

    // stage 2: top-32 of the 119 pruned cartesian sums (R2-verified)
    float cv[2]; int cc[2];
    #pragma unroll
    for (int t = 0; t < 2; ++t) {
        const int c = t * 64 + lane;
        int ii = -1, jj = 0, off = 0;
        #pragma unroll
        for (int i = 0; i < 32; ++i) {
            const int cnt = 32 / (i + 1);
            const bool in = (c >= off) && (c < off + cnt);
            ii = in ? i : ii;
            jj = in ? c - off : jj;
            off += cnt;
        }
        if (ii >= 0) { cv[t] = ts[0][ii] + ts[1][jj]; cc[t] = ii * 32 + jj; }
        else         { cv[t] = -INFINITY;             cc[t] = 0x7fffffff;  }
    }

    unsigned used2 = 0;
    float mval = 0.f, myval = -INFINITY;
    int mycombo = 0;
    for (int it = 0; it < KNN; ++it) {
        float bv = -INFINITY; int bc = 0x7fffffff;
        #pragma unroll
        for (int t = 0; t < 2; ++t) {
            const bool live = !((used2 >> t) & 1u);
            const bool better = live &&
                (cv[t] > bv || (cv[t] == bv && cc[t] < bc));
            bv = better ? cv[t] : bv;
            bc = better ? cc[t] : bc;
        }
        float m = bv;
        #pragma unroll
        for (int off = 32; off; off >>= 1) m = fmaxf(m, __shfl_xor(m, off));
        const unsigned long long bal = __ballot(bv == m);
        int combo;
        if (__popcll(bal) == 1) {
            combo = __shfl(bc, (int)(__ffsll(bal) - 1));
        } else {
            unsigned cm = (bv == m) ? (unsigned)bc : 0xffffffffu;
            #pragma unroll
            for (int off = 32; off; off >>= 1) cm = min(cm, __shfl_xor(cm, off));
            combo = (int)cm;
        }
        if (it == 0) mval = m;
        if (lane == it) { myval = m; mycombo = combo; }
        #pragma unroll
        for (int t = 0; t < 2; ++t)
            if (cc[t] == combo) used2 |= 1u << t;
    }

    const float ew = (lane < KNN) ? expf(myval - mval) : 0.f;
    float ssum = ew;
    #pragma unroll
    for (int off = 32; off; off >>= 1) ssum += __shfl_xor(ssum, off);
    if (lane < KNN) {
        const int i1 = ti[0][mycombo >> 5];
        const int i2 = ti[1][mycombo & 31];
        w_out[(size_t)nh * KNN + lane] = ew / ssum;
        idx_out[(size_t)nh * KNN + lane] = i1 * NKEYS + i2;
    }
}

// =========== weighted embedding-bag gather + gate -> bf16 hi/lo out0 =======
__global__ __launch_bounds__(256)
void gather_kernel(const float* __restrict__ values,
                   const float* __restrict__ w, const int* __restrict__ idx,
                   const float* __restrict__ gate,
                   unsigned short* __restrict__ o0h, unsigned short* __restrict__ o0l)
{
    const int n = blockIdx.x;
    const int t = threadIdx.x;
    __shared__ float sw[HEADS * KNN];
    __shared__ int   sidx[HEADS * KNN];
    if (t < HEADS * KNN) {
        sw[t]   = w[(size_t)n * HEADS * KNN + t];
        sidx[t] = idx[(size_t)n * HEADS * KNN + t];
    }
    __syncthreads();
    const int d0 = t * 2;
    float2 acc = {0.f, 0.f};
    #pragma unroll 8
    for (int k = 0; k < HEADS * KNN; ++k) {
        const float2 v = *(const float2*)(values + (size_t)sidx[k] * DOUT + d0);
        const float ww = sw[k];
        acc.x = fmaf(ww, v.x, acc.x);
        acc.y = fmaf(ww, v.y, acc.y);
    }
    const float2 g = *(const float2*)(gate + (size_t)n * DOUT + d0);
    const float vx = acc.x * g.x;
    const float vy = acc.y * g.y;
    ushort2 h, l;
    h.x = f2bf(vx); l.x = f2bf(vx - bf2f(h.x));
    h.y = f2bf(vy); l.y = f2bf(vy - bf2f(h.y));
    *(ushort2*)(o0h + (size_t)n * DOUT + d0) = h;
    *(ushort2*)(o0l + (size_t)n * DOUT + d0) = l;
}

// =========== final projection: out = out0 @ Wv^T + bv (3-term MFMA) ========
__global__ __launch_bounds__(256)
void mfma_out(const unsigned short* __restrict__ o0h, const unsigned short* __restrict__ o0l,
              const unsigned short* __restrict__ vh, const unsigned short* __restrict__ vl,
              const float* __restrict__ bv, float* __restrict__ out)
{
    __shared__ __align__(16) unsigned short Al[64 * 64];
    __shared__ __align__(16) unsigned short Bl[64 * 64];
    const int tid = threadIdx.x;
    const int wid = tid >> 6, lane = tid & 63;
    const int r16 = lane & 15, kc = lane >> 4;
    const int wr = wid >> 1, wc = wid & 1;
    const int m0 = blockIdx.x * 64, n0 = blockIdx.y * 64;
    const int srow = tid >> 2;
    const int skb  = (tid & 3) << 4;
    const unsigned swzw = (unsigned)((srow & 7) << 4);

    f32x4 acc[2][2] = {};
    #pragma unroll
    for (int term = 0; term < 3; ++term) {
        const unsigned short* Ag = ((term == 2) ? o0l : o0h) + (size_t)(m0 + srow) * DOUT + skb;
        const unsigned short* Bg = ((term == 1) ? vl : vh) + (size_t)(n0 + srow) * DOUT + skb;
        for (int k0 = 0; k0 < DOUT; k0 += 64) {
            __syncthreads();
            const uint4 va0 = *(const uint4*)(Ag + k0);
            const uint4 va1 = *(const uint4*)(Ag + k0 + 8);
            const uint4 vb0 = *(const uint4*)(Bg + k0);
            const uint4 vb1 = *(const uint4*)(Bg + k0 + 8);
            const unsigned b0 = (unsigned)(srow * 128 + skb * 2) ^ swzw;
            const unsigned b1 = (unsigned)(srow * 128 + skb * 2 + 16) ^ swzw;
            *(uint4*)((char*)Al + b0) = va0; *(uint4*)((char*)Al + b1) = va1;
            *(uint4*)((char*)Bl + b0) = vb0; *(uint4*)((char*)Bl + b1) = vb1;
            __syncthreads();
            #pragma unroll
            for (int ks = 0; ks < 2; ++ks) {
                bf16x8 af[2], bf[2];
                #pragma unroll
                for (int f = 0; f < 2; ++f) {
                    const int am = wr * 32 + f * 16 + r16;
                    af[f] = *(const bf16x8*)((const char*)Al +
                        ((unsigned)(am * 128 + ks * 64 + kc * 16) ^ ((am & 7) << 4)));
                    const int bn = wc * 32 + f * 16 + r16;
                    bf[f] = *(const bf16x8*)((const char*)Bl +
                        ((unsigned)(bn * 128 + ks * 64 + kc * 16) ^ ((bn & 7) << 4)));
                }
                #pragma unroll
                for (int fm = 0; fm < 2; ++fm)
                    #pragma unroll
                    for (int fn = 0; fn < 2; ++fn)
                        acc[fm][fn] = __builtin_amdgcn_mfma_f32_16x16x32_bf16(
                            af[fm], bf[fn], acc[fm][fn], 0, 0, 0);
            }
        }
    }

    #pragma unroll
    for (int fm = 0; fm < 2; ++fm) {
        const int row = m0 + wr * 32 + fm * 16 + kc * 4;
        #pragma unroll
        for (int fn = 0; fn < 2; ++fn) {
            const int col = n0 + wc * 32 + fn * 16 + r16;
            const float b = bv[col];
            #pragma unroll
            for (int r = 0; r < 4; ++r)
                out[(size_t)(row + r) * DOUT + col] = acc[fm][fn][r] + b;
        }
    }
}

}  // namespace

extern "C" void kernel_launch(void* const* d_in, const int* in_sizes, int n_in,
                              void* d_out, int out_size, void* d_ws, size_t ws_size,
                              hipStream_t stream)
{
    const float* x      = (const float*)d_in[0];
    const float* Wq     = (const float*)d_in[1];
    const float* bq     = (const float*)d_in[2];
    const float* keys   = (const float*)d_in[3];
    const float* values = (const float*)d_in[4];
    const float* Wsw    = (const float*)d_in[5];
    const float* bsw    = (const float*)d_in[6];
    const float* Wv     = (const float*)d_in[7];
    const float* bv     = (const float*)d_in[8];
    float* out = (float*)d_out;

    // workspace layout
    float*          q    = (float*)d_ws;                                        // 16MB
    unsigned short* qh   = (unsigned short*)(q + (size_t)NROWS * HEADS * KDIM); // 8MB
    float*          s    = (float*)(qh + (size_t)NROWS * HEADS * KDIM);         // 32MB
    unsigned short* xh   = (unsigned short*)(s + (size_t)NROWS * HEADS * 2 * NKEYS);
    unsigned short* xl   = xh + (size_t)NROWS * DIN;
    unsigned short* wh   = xl + (size_t)NROWS * DIN;
    unsigned short* wl   = wh + (size_t)DOUT * DIN;
    unsigned short* kh   = wl + (size_t)DOUT * DIN;
    unsigned short* vh   = kh + (size_t)8 * NKEYS * HALFD;
    unsigned short* vl   = vh + (size_t)DOUT * DOUT;
    float*          wsc  = (float*)(vl + (size_t)DOUT * DOUT);
    int*            idxb = (int*)(wsc + (size_t)NROWS * HEADS * KNN);
    float*          gate = (float*)(idxb + (size_t)NROWS * HEADS * KNN);
    unsigned short* o0h  = (unsigned short*)(gate + (size_t)NROWS * DOUT);
    unsigned short* o0l  = o0h + (size_t)NROWS * DOUT;

    const dim3 blk(256);

    // 1) split x/Wsw/Wv -> bf16 hi+lo; keys -> bf16 hi
    split4<<<dim3(1024, 1, 4), blk, 0, stream>>>(
        x, Wsw, keys, Wv, xh, xl, wh, wl, kh, vh, vl);

    // 2) q = x @ Wq^T + bq  (exact f32 ascending chain, 1024 blocks) + bf16-hi
    gemm_q<<<dim3(32, 32), blk, 0, stream>>>(x, Wq, q, qh, bq);

    // 3) approx scores (z<8, bf16 1-term) + gate (z==8, 3-term) — LDS MFMA
    mfma_sg<<<dim3(16, 4, 9), blk, 0, stream>>>(
        qh, kh, xh, xl, wh, wl, bsw, s, gate);

    // 4) tau-select -> exact rescore -> bitonic top-32 -> stage 2 + softmax
    topk3<<<dim3(NROWS * HEADS), dim3(64), 0, stream>>>(
        s, q, keys, wsc, idxb);

    // 5) out0 = (sum_k w*values[idx]) * gate  -> bf16 hi/lo
    gather_kernel<<<dim3(NROWS), blk, 0, stream>>>(
        values, wsc, idxb, gate, o0h, o0l);

    // 6) out = out0 @ Wv^T + bv  (3-term split MFMA)
    mfma_out<<<dim3(32, 8), blk, 0, stream>>>(o0h, o0l, vh, vl, bv, out);
}

// Round 11
// 309.190 us; speedup vs baseline: 1.5470x; 1.0973x over previous
//
#include <hip/hip_runtime.h>
#include <math.h>

namespace {

constexpr int NROWS = 2048;   // B*T
constexpr int DIN   = 512;
constexpr int DOUT  = 512;
constexpr int HEADS = 4;
constexpr int KDIM  = 512;
constexpr int HALFD = 256;
constexpr int NKEYS = 512;
constexpr int KNN   = 32;

typedef short bf16x8 __attribute__((ext_vector_type(8)));
typedef float f32x4  __attribute__((ext_vector_type(4)));

__device__ inline unsigned short f2bf(float f) {   // round-to-nearest-even
    unsigned u = __float_as_uint(f);
    unsigned r = u + 0x7FFFu + ((u >> 16) & 1u);
    return (unsigned short)(r >> 16);
}
__device__ inline float bf2f(unsigned short h) {
    return __uint_as_float((unsigned)h << 16);
}
__device__ inline unsigned fmap(float f) {
    unsigned u = __float_as_uint(f);
    return (u & 0x80000000u) ? ~u : (u | 0x80000000u);
}
__device__ inline float funmap(unsigned m) {
    unsigned u = (m & 0x80000000u) ? (m & 0x7FFFFFFFu) : ~m;
    return __uint_as_float(u);
}
__device__ inline unsigned long long shflxor64(unsigned long long x, int m) {
    unsigned lo = (unsigned)x, hi = (unsigned)(x >> 32);
    lo = __shfl_xor(lo, m);
    hi = __shfl_xor(hi, m);
    return ((unsigned long long)hi << 32) | lo;
}
// full 64-lane bitonic sort, descending by u64 key; lane l ends with rank-l
__device__ inline unsigned long long bitonic64_desc(unsigned long long v, int lane) {
    #pragma unroll
    for (int k = 2; k <= 64; k <<= 1) {
        #pragma unroll
        for (int j = k >> 1; j > 0; j >>= 1) {
            const unsigned long long o = shflxor64(v, j);
            const bool keepMax = (((lane & j) == 0) == ((lane & k) == 0));
            const bool oGreater = o > v;
            v = (keepMax == oGreater) ? o : v;
        }
    }
    return v;
}

// ====== split: x->h/m (z0), Wsw->h/m (z1), keys->h/m/l (z2), Wv->h/m (z3) ==
__global__ __launch_bounds__(256)
void split5(const float* __restrict__ x, const float* __restrict__ wsw,
            const float* __restrict__ keys, const float* __restrict__ wv,
            unsigned short* __restrict__ xh, unsigned short* __restrict__ xm,
            unsigned short* __restrict__ wh, unsigned short* __restrict__ wm,
            unsigned short* __restrict__ kh, unsigned short* __restrict__ km,
            unsigned short* __restrict__ kl,
            unsigned short* __restrict__ vh, unsigned short* __restrict__ vm)
{
    const int z = blockIdx.z;
    const int i = (blockIdx.x * 256 + threadIdx.x) * 4;
    if (z == 2) {                      // keys -> 3-way (24+ mantissa bits)
        if (i >= 1048576) return;
        const float4 v = *(const float4*)(keys + i);
        ushort4 oh, om, ol;
        float r;
        oh.x = f2bf(v.x); r = v.x - bf2f(oh.x); om.x = f2bf(r); ol.x = f2bf(r - bf2f(om.x));
        oh.y = f2bf(v.y); r = v.y - bf2f(oh.y); om.y = f2bf(r); ol.y = f2bf(r - bf2f(om.y));
        oh.z = f2bf(v.z); r = v.z - bf2f(oh.z); om.z = f2bf(r); ol.z = f2bf(r - bf2f(om.z));
        oh.w = f2bf(v.w); r = v.w - bf2f(oh.w); om.w = f2bf(r); ol.w = f2bf(r - bf2f(om.w));
        *(ushort4*)(kh + i) = oh;
        *(ushort4*)(km + i) = om;
        *(ushort4*)(kl + i) = ol;
        return;
    }
    const float* src = (z == 0) ? x : (z == 1) ? wsw : wv;
    unsigned short* ph = (z == 0) ? xh : (z == 1) ? wh : vh;
    unsigned short* pm = (z == 0) ? xm : (z == 1) ? wm : vm;
    const int n = (z == 0) ? 1048576 : 262144;
    if (i >= n) return;
    const float4 v = *(const float4*)(src + i);
    ushort4 oh, om;
    oh.x = f2bf(v.x); om.x = f2bf(v.x - bf2f(oh.x));
    oh.y = f2bf(v.y); om.y = f2bf(v.y - bf2f(oh.y));
    oh.z = f2bf(v.z); om.z = f2bf(v.z - bf2f(oh.z));
    oh.w = f2bf(v.w); om.w = f2bf(v.w - bf2f(oh.w));
    *(ushort4*)(ph + i) = oh;
    *(ushort4*)(pm + i) = om;
}

// ===== q GEMM: 64x64 tile f32 (R10-proven), epilogue -> 3-way bf16 split ====
__global__ __launch_bounds__(256)
void gemm_q(const float* __restrict__ A, const float* __restrict__ B,
            unsigned short* __restrict__ Ch, unsigned short* __restrict__ Cm,
            unsigned short* __restrict__ Cl, const float* __restrict__ bias)
{
    constexpr int ldc = HEADS * KDIM, K = DIN;
    __shared__ __align__(16) float as[16][68];
    __shared__ __align__(16) float bs[16][68];
    const int tid = threadIdx.x;
    const int tx = tid & 15, ty = tid >> 4;
    const int m0 = blockIdx.y * 64, n0 = blockIdx.x * 64;
    const int lrow = tid >> 2;
    const int lk4  = (tid & 3) << 2;
    const float* Ap = A + (size_t)(m0 + lrow) * DIN + lk4;
    const float* Bp = B + (size_t)(n0 + lrow) * DIN + lk4;
    float acc[4][4] = {};

    float4 av = *(const float4*)(Ap);
    float4 bv = *(const float4*)(Bp);
    for (int k0 = 0; k0 < K; k0 += 16) {
        __syncthreads();
        as[lk4 + 0][lrow] = av.x; as[lk4 + 1][lrow] = av.y;
        as[lk4 + 2][lrow] = av.z; as[lk4 + 3][lrow] = av.w;
        bs[lk4 + 0][lrow] = bv.x; bs[lk4 + 1][lrow] = bv.y;
        bs[lk4 + 2][lrow] = bv.z; bs[lk4 + 3][lrow] = bv.w;
        __syncthreads();
        if (k0 + 16 < K) {
            av = *(const float4*)(Ap + k0 + 16);
            bv = *(const float4*)(Bp + k0 + 16);
        }
        #pragma unroll
        for (int kk = 0; kk < 16; ++kk) {
            const float4 a = *(const float4*)&as[kk][ty << 2];
            const float4 b = *(const float4*)&bs[kk][tx << 2];
            const float ar[4] = {a.x, a.y, a.z, a.w};
            const float br[4] = {b.x, b.y, b.z, b.w};
            #pragma unroll
            for (int i = 0; i < 4; ++i)
                #pragma unroll
                for (int j = 0; j < 4; ++j)
                    acc[i][j] = fmaf(ar[i], br[j], acc[i][j]);
        }
    }

    const float4 bb = *(const float4*)(bias + n0 + (tx << 2));
    #pragma unroll
    for (int i = 0; i < 4; ++i) {
        const float o[4] = {acc[i][0] + bb.x, acc[i][1] + bb.y,
                            acc[i][2] + bb.z, acc[i][3] + bb.w};
        ushort4 h, m, l;
        unsigned short* hp = (unsigned short*)&h;
        unsigned short* mp = (unsigned short*)&m;
        unsigned short* lp = (unsigned short*)&l;
        #pragma unroll
        for (int j = 0; j < 4; ++j) {
            hp[j] = f2bf(o[j]);
            const float r = o[j] - bf2f(hp[j]);
            mp[j] = f2bf(r);
            lp[j] = f2bf(r - bf2f(mp[j]));
        }
        const size_t off = (size_t)(m0 + (ty << 2) + i) * ldc + n0 + (tx << 2);
        *(ushort4*)(Ch + off) = h;
        *(ushort4*)(Cm + off) = m;
        *(ushort4*)(Cl + off) = l;
    }
}

// ============ LDS-staged bf16 MFMA: scores (z<8, 6-term triple-split) ======
// z==8: gate = silu(3-term) (R8-proven geometry: 128x128, BK=64, T2 swizzle)
__global__ __launch_bounds__(256)
void mfma_sg(const unsigned short* __restrict__ qh, const unsigned short* __restrict__ qm,
             const unsigned short* __restrict__ ql,
             const unsigned short* __restrict__ kh, const unsigned short* __restrict__ km,
             const unsigned short* __restrict__ kl,
             const unsigned short* __restrict__ xh, const unsigned short* __restrict__ xm,
             const unsigned short* __restrict__ wh, const unsigned short* __restrict__ wm,
             const float* __restrict__ bsw,
             float* __restrict__ s, float* __restrict__ gate)
{
    __shared__ __align__(16) unsigned short Al[128 * 64];
    __shared__ __align__(16) unsigned short Bl[128 * 64];
    const int tid  = threadIdx.x;
    const int wid  = tid >> 6, lane = tid & 63;
    const int r16  = lane & 15, kc = lane >> 4;
    const int wr   = wid >> 1, wc = wid & 1;
    const int z    = blockIdx.z;
    const int bx   = blockIdx.x, by = blockIdx.y;
    const int srow = tid >> 1;
    const int skb  = (tid & 1) << 5;
    const unsigned swzw = (unsigned)((srow & 7) << 4);

    // term tables: A-variant / B-variant indices
    constexpr int TA[6] = {0, 0, 1, 0, 2, 1};
    constexpr int TB[6] = {0, 1, 0, 2, 0, 1};
    const unsigned short* As[3];
    const unsigned short* Bs[3];
    int K, nterm;
    size_t aoff, boff;
    if (z < 8) {
        As[0] = qh; As[1] = qm; As[2] = ql;
        Bs[0] = kh; Bs[1] = km; Bs[2] = kl;
        K = HALFD; nterm = 6;
        aoff = (size_t)(bx * 128 + srow) * (HEADS * KDIM)
             + (z >> 1) * KDIM + (z & 1) * HALFD + skb;
        boff = ((size_t)z * NKEYS + by * 128 + srow) * HALFD + skb;
    } else {
        As[0] = xh; As[1] = xm; As[2] = nullptr;
        Bs[0] = wh; Bs[1] = wm; Bs[2] = nullptr;
        K = DIN; nterm = 3;
        aoff = (size_t)(bx * 128 + srow) * DIN + skb;
        boff = (size_t)(by * 128 + srow) * DIN + skb;
    }

    f32x4 acc[4][4] = {};
    for (int term = 0; term < nterm; ++term) {
        const unsigned short* Ag = As[TA[term]] + aoff;
        const unsigned short* Bg = Bs[TB[term]] + boff;
        for (int k0 = 0; k0 < K; k0 += 64) {
            __syncthreads();
            #pragma unroll
            for (int j = 0; j < 4; ++j) {
                const uint4 va = *(const uint4*)(Ag + k0 + j * 8);
                const uint4 vb = *(const uint4*)(Bg + k0 + j * 8);
                const unsigned boff2 = (unsigned)(srow * 128 + (skb + j * 8) * 2) ^ swzw;
                *(uint4*)((char*)Al + boff2) = va;
                *(uint4*)((char*)Bl + boff2) = vb;
            }
            __syncthreads();
            #pragma unroll
            for (int ks = 0; ks < 2; ++ks) {
                bf16x8 af[4], bf[4];
                #pragma unroll
                for (int f = 0; f < 4; ++f) {
                    const int am = wr * 64 + f * 16 + r16;
                    af[f] = *(const bf16x8*)((const char*)Al +
                        ((unsigned)(am * 128 + ks * 64 + kc * 16) ^ ((am & 7) << 4)));
                    const int bn = wc * 64 + f * 16 + r16;
                    bf[f] = *(const bf16x8*)((const char*)Bl +
                        ((unsigned)(bn * 128 + ks * 64 + kc * 16) ^ ((bn & 7) << 4)));
                }
                #pragma unroll
                for (int fm = 0; fm < 4; ++fm)
                    #pragma unroll
                    for (int fn = 0; fn < 4; ++fn)
                        acc[fm][fn] = __builtin_amdgcn_mfma_f32_16x16x32_bf16(
                            af[fm], bf[fn], acc[fm][fn], 0, 0, 0);
            }
        }
    }

    #pragma unroll
    for (int fm = 0; fm < 4; ++fm) {
        const int row = bx * 128 + wr * 64 + fm * 16 + kc * 4;
        #pragma unroll
        for (int fn = 0; fn < 4; ++fn) {
            const int col = by * 128 + wc * 64 + fn * 16 + r16;
            #pragma unroll
            for (int r = 0; r < 4; ++r) {
                float v = acc[fm][fn][r];
                if (z < 8) {
                    s[(size_t)(row + r) * (HEADS * 2 * NKEYS) + z * NKEYS + col] = v;
                } else {
                    v += bsw[col];
                    v = v / (1.f + expf(-v));
                    gate[(size_t)(row + r) * DOUT + col] = v;
                }
            }
        }
    }
}

// ====== topk4: tau-select [32,64] -> bitonic top-32 -> stage 2 + softmax ===
// Scores s are now accurate to ~3e-7 (6-term triple-split) -> used directly.
__global__ __launch_bounds__(64)
void topk4(const float* __restrict__ s,
           float* __restrict__ w_out, int* __restrict__ idx_out)
{
    const int nh   = blockIdx.x;
    const int lane = threadIdx.x;
    const int sub  = lane >> 5;
    const int sl   = lane & 31;
    __shared__ unsigned long long pkl[2][64];
    __shared__ float ts[2][KNN];
    __shared__ int   ti[2][KNN];

    const float* sb = s + (size_t)nh * (2 * NKEYS) + sub * NKEYS;
    unsigned u[16];
    #pragma unroll
    for (int i = 0; i < 16; ++i) u[i] = fmap(sb[i * 32 + sl]);

    // tau-bisect: count(u >= tau) in [32,64] per half
    unsigned lo = 0, hi = 0xFFFFFFFFu, tau = 0;
    bool found = false;
    for (int iter = 0; iter < 30; ++iter) {
        if (__all(found)) break;
        const unsigned mid = lo + ((hi - lo) >> 1);
        int c = 0;
        #pragma unroll
        for (int i = 0; i < 16; ++i) c += (u[i] >= mid) ? 1 : 0;
        #pragma unroll
        for (int off = 1; off <= 16; off <<= 1) c += __shfl_xor(c, off);
        if (!found) {
            if (c >= 32 && c <= 64) { tau = mid; found = true; }
            else if (c > 64) lo = mid + 1;
            else hi = mid - 1;
        }
    }
    if (!found) tau = lo;

    // zero pad slots, then ballot-compact (value,index) packed u64
    pkl[0][lane] = 0ull;
    pkl[1][lane] = 0ull;
    __syncthreads();
    unsigned msk = 0;
    #pragma unroll
    for (int i = 0; i < 16; ++i) msk |= (u[i] >= tau ? 1u : 0u) << i;
    int mc = __popc(msk);
    int pfx = mc;
    #pragma unroll
    for (int d = 1; d <= 16; d <<= 1) {
        const int t = __shfl_up(pfx, d);
        if (sl >= d) pfx += t;
    }
    int slot = pfx - mc;
    #pragma unroll
    for (int i = 0; i < 16; ++i)
        if ((msk >> i) & 1u) {
            if (slot < 64)
                pkl[sub][slot] = ((unsigned long long)u[i] << 32)
                               | (unsigned)(~((i << 5) | sl));
            ++slot;
        }
    __syncthreads();

    // bitonic-64 descending per half; lane<32 holds exact top-32
    #pragma unroll
    for (int p = 0; p < 2; ++p) {
        unsigned long long v = bitonic64_desc(pkl[p][lane], lane);
        if (lane < KNN) {
            ts[p][lane] = funmap((unsigned)(v >> 32));
            ti[p][lane] = (int)(~(unsigned)v) & (NKEYS - 1);
        }
    }
    __syncthreads();

    // stage 2: top-32 of the 119 pruned cartesian sums (R2/R10-proven)
    float cv[2]; int cc[2];
    #pragma unroll
    for (int t = 0; t < 2; ++t) {
        const int c = t * 64 + lane;
        int ii = -1, jj = 0, off = 0;
        #pragma unroll
        for (int i = 0; i < 32; ++i) {
            const int cnt = 32 / (i + 1);
            const bool in = (c >= off) && (c < off + cnt);
            ii = in ? i : ii;
            jj = in ? c - off : jj;
            off += cnt;
        }
        if (ii >= 0) { cv[t] = ts[0][ii] + ts[1][jj]; cc[t] = ii * 32 + jj; }
        else         { cv[t] = -INFINITY;             cc[t] = 0x7fffffff;  }
    }

    unsigned used2 = 0;
    float mval = 0.f, myval = -INFINITY;
    int mycombo = 0;
    for (int it = 0; it < KNN; ++it) {
        float bv = -INFINITY; int bc = 0x7fffffff;
        #pragma unroll
        for (int t = 0; t < 2; ++t) {
            const bool live = !((used2 >> t) & 1u);
            const bool better = live &&
                (cv[t] > bv || (cv[t] == bv && cc[t] < bc));
            bv = better ? cv[t] : bv;
            bc = better ? cc[t] : bc;
        }
        float m = bv;
        #pragma unroll
        for (int off = 32; off; off >>= 1) m = fmaxf(m, __shfl_xor(m, off));
        const unsigned long long bal = __ballot(bv == m);
        int combo;
        if (__popcll(bal) == 1) {
            combo = __shfl(bc, (int)(__ffsll(bal) - 1));
        } else {
            unsigned cm = (bv == m) ? (unsigned)bc : 0xffffffffu;
            #pragma unroll
            for (int off = 32; off; off >>= 1) cm = min(cm, __shfl_xor(cm, off));
            combo = (int)cm;
        }
        if (it == 0) mval = m;
        if (lane == it) { myval = m; mycombo = combo; }
        #pragma unroll
        for (int t = 0; t < 2; ++t)
            if (cc[t] == combo) used2 |= 1u << t;
    }

    const float ew = (lane < KNN) ? expf(myval - mval) : 0.f;
    float ssum = ew;
    #pragma unroll
    for (int off = 32; off; off >>= 1) ssum += __shfl_xor(ssum, off);
    if (lane < KNN) {
        const int i1 = ti[0][mycombo >> 5];
        const int i2 = ti[1][mycombo & 31];
        w_out[(size_t)nh * KNN + lane] = ew / ssum;
        idx_out[(size_t)nh * KNN + lane] = i1 * NKEYS + i2;
    }
}

// =========== weighted embedding-bag gather + gate -> bf16 hi/lo out0 =======
__global__ __launch_bounds__(256)
void gather_kernel(const float* __restrict__ values,
                   const float* __restrict__ w, const int* __restrict__ idx,
                   const float* __restrict__ gate,
                   unsigned short* __restrict__ o0h, unsigned short* __restrict__ o0l)
{
    const int n = blockIdx.x;
    const int t = threadIdx.x;
    __shared__ float sw[HEADS * KNN];
    __shared__ int   sidx[HEADS * KNN];
    if (t < HEADS * KNN) {
        sw[t]   = w[(size_t)n * HEADS * KNN + t];
        sidx[t] = idx[(size_t)n * HEADS * KNN + t];
    }
    __syncthreads();
    const int d0 = t * 2;
    float2 acc = {0.f, 0.f};
    #pragma unroll 8
    for (int k = 0; k < HEADS * KNN; ++k) {
        const float2 v = *(const float2*)(values + (size_t)sidx[k] * DOUT + d0);
        const float ww = sw[k];
        acc.x = fmaf(ww, v.x, acc.x);
        acc.y = fmaf(ww, v.y, acc.y);
    }
    const float2 g = *(const float2*)(gate + (size_t)n * DOUT + d0);
    const float vx = acc.x * g.x;
    const float vy = acc.y * g.y;
    ushort2 h, l;
    h.x = f2bf(vx); l.x = f2bf(vx - bf2f(h.x));
    h.y = f2bf(vy); l.y = f2bf(vy - bf2f(h.y));
    *(ushort2*)(o0h + (size_t)n * DOUT + d0) = h;
    *(ushort2*)(o0l + (size_t)n * DOUT + d0) = l;
}

// =========== final projection: out = out0 @ Wv^T + bv (3-term MFMA) ========
__global__ __launch_bounds__(256)
void mfma_out(const unsigned short* __restrict__ o0h, const unsigned short* __restrict__ o0l,
              const unsigned short* __restrict__ vh, const unsigned short* __restrict__ vm,
              const float* __restrict__ bv, float* __restrict__ out)
{
    __shared__ __align__(16) unsigned short Al[64 * 64];
    __shared__ __align__(16) unsigned short Bl[64 * 64];
    const int tid = threadIdx.x;
    const int wid = tid >> 6, lane = tid & 63;
    const int r16 = lane & 15, kc = lane >> 4;
    const int wr = wid >> 1, wc = wid & 1;
    const int m0 = blockIdx.x * 64, n0 = blockIdx.y * 64;
    const int srow = tid >> 2;
    const int skb  = (tid & 3) << 4;
    const unsigned swzw = (unsigned)((srow & 7) << 4);

    f32x4 acc[2][2] = {};
    #pragma unroll
    for (int term = 0; term < 3; ++term) {
        const unsigned short* Ag = ((term == 2) ? o0l : o0h) + (size_t)(m0 + srow) * DOUT + skb;
        const unsigned short* Bg = ((term == 1) ? vm : vh) + (size_t)(n0 + srow) * DOUT + skb;
        for (int k0 = 0; k0 < DOUT; k0 += 64) {
            __syncthreads();
            const uint4 va0 = *(const uint4*)(Ag + k0);
            const uint4 va1 = *(const uint4*)(Ag + k0 + 8);
            const uint4 vb0 = *(const uint4*)(Bg + k0);
            const uint4 vb1 = *(const uint4*)(Bg + k0 + 8);
            const unsigned b0 = (unsigned)(srow * 128 + skb * 2) ^ swzw;
            const unsigned b1 = (unsigned)(srow * 128 + skb * 2 + 16) ^ swzw;
            *(uint4*)((char*)Al + b0) = va0; *(uint4*)((char*)Al + b1) = va1;
            *(uint4*)((char*)Bl + b0) = vb0; *(uint4*)((char*)Bl + b1) = vb1;
            __syncthreads();
            #pragma unroll
            for (int ks = 0; ks < 2; ++ks) {
                bf16x8 af[2], bf[2];
                #pragma unroll
                for (int f = 0; f < 2; ++f) {
                    const int am = wr * 32 + f * 16 + r16;
                    af[f] = *(const bf16x8*)((const char*)Al +
                        ((unsigned)(am * 128 + ks * 64 + kc * 16) ^ ((am & 7) << 4)));
                    const int bn = wc * 32 + f * 16 + r16;
                    bf[f] = *(const bf16x8*)((const char*)Bl +
                        ((unsigned)(bn * 128 + ks * 64 + kc * 16) ^ ((bn & 7) << 4)));
                }
                #pragma unroll
                for (int fm = 0; fm < 2; ++fm)
                    #pragma unroll
                    for (int fn = 0; fn < 2; ++fn)
                        acc[fm][fn] = __builtin_amdgcn_mfma_f32_16x16x32_bf16(
                            af[fm], bf[fn], acc[fm][fn], 0, 0, 0);
            }
        }
    }

    #pragma unroll
    for (int fm = 0; fm < 2; ++fm) {
        const int row = m0 + wr * 32 + fm * 16 + kc * 4;
        #pragma unroll
        for (int fn = 0; fn < 2; ++fn) {
            const int col = n0 + wc * 32 + fn * 16 + r16;
            const float b = bv[col];
            #pragma unroll
            for (int r = 0; r < 4; ++r)
                out[(size_t)(row + r) * DOUT + col] = acc[fm][fn][r] + b;
        }
    }
}

}  // namespace

extern "C" void kernel_launch(void* const* d_in, const int* in_sizes, int n_in,
                              void* d_out, int out_size, void* d_ws, size_t ws_size,
                              hipStream_t stream)
{
    const float* x      = (const float*)d_in[0];
    const float* Wq     = (const float*)d_in[1];
    const float* bq     = (const float*)d_in[2];
    const float* keys   = (const float*)d_in[3];
    const float* values = (const float*)d_in[4];
    const float* Wsw    = (const float*)d_in[5];
    const float* bsw    = (const float*)d_in[6];
    const float* Wv     = (const float*)d_in[7];
    const float* bv     = (const float*)d_in[8];
    float* out = (float*)d_out;

    // workspace layout (all bf16 arrays 16B-aligned by construction)
    unsigned short* qh  = (unsigned short*)d_ws;                      // 8MB
    unsigned short* qm  = qh + (size_t)NROWS * HEADS * KDIM;          // 8MB
    unsigned short* ql  = qm + (size_t)NROWS * HEADS * KDIM;          // 8MB
    float*          s   = (float*)(ql + (size_t)NROWS * HEADS * KDIM); // 32MB
    unsigned short* xh  = (unsigned short*)(s + (size_t)NROWS * HEADS * 2 * NKEYS);
    unsigned short* xm  = xh + (size_t)NROWS * DIN;
    unsigned short* wh  = xm + (size_t)NROWS * DIN;
    unsigned short* wm  = wh + (size_t)DOUT * DIN;
    unsigned short* kh  = wm + (size_t)DOUT * DIN;
    unsigned short* km  = kh + (size_t)8 * NKEYS * HALFD;
    unsigned short* kl  = km + (size_t)8 * NKEYS * HALFD;
    unsigned short* vh  = kl + (size_t)8 * NKEYS * HALFD;
    unsigned short* vm  = vh + (size_t)DOUT * DOUT;
    float*          wsc = (float*)(vm + (size_t)DOUT * DOUT);
    int*            idxb = (int*)(wsc + (size_t)NROWS * HEADS * KNN);
    float*          gate = (float*)(idxb + (size_t)NROWS * HEADS * KNN);
    unsigned short* o0h  = (unsigned short*)(gate + (size_t)NROWS * DOUT);
    unsigned short* o0l  = o0h + (size_t)NROWS * DOUT;

    const dim3 blk(256);

    // 1) splits: x/Wsw/Wv 2-way, keys 3-way
    split5<<<dim3(1024, 1, 4), blk, 0, stream>>>(
        x, Wsw, keys, Wv, xh, xm, wh, wm, kh, km, kl, vh, vm);

    // 2) q = x @ Wq^T + bq (exact f32) -> 3-way bf16 split
    gemm_q<<<dim3(32, 32), blk, 0, stream>>>(x, Wq, qh, qm, ql, bq);

    // 3) scores (z<8, 6-term triple-split MFMA) + gate (z==8, 3-term)
    mfma_sg<<<dim3(16, 4, 9), blk, 0, stream>>>(
        qh, qm, ql, kh, km, kl, xh, xm, wh, wm, bsw, s, gate);

    // 4) tau-select -> bitonic exact top-32 -> stage 2 + softmax
    topk4<<<dim3(NROWS * HEADS), dim3(64), 0, stream>>>(s, wsc, idxb);

    // 5) out0 = (sum_k w*values[idx]) * gate  -> bf16 hi/lo
    gather_kernel<<<dim3(NROWS), blk, 0, stream>>>(
        values, wsc, idxb, gate, o0h, o0l);

    // 6) out = out0 @ Wv^T + bv  (3-term split MFMA)
    mfma_out<<<dim3(32, 8), blk, 0, stream>>>(o0h, o0l, vh, vm, bv, out);
}